// Round 18
// baseline (178.589 us; speedup 1.0000x reference)
//
#include <hip/hip_runtime.h>
#include <hip/hip_bf16.h>
#include <cstdint>

#define NH 12
#define DH 64
#define TSEQ 4096
#define BATCH 2
#define CDIM 768
#define MROWS (BATCH*TSEQ)

typedef __bf16 bf16x8 __attribute__((ext_vector_type(8)));
typedef __bf16 bf16x4 __attribute__((ext_vector_type(4)));
typedef bf16x8 bf16x8_a __attribute__((may_alias));
typedef bf16x4 bf16x4_a __attribute__((may_alias));
typedef float f32x4 __attribute__((ext_vector_type(4)));
typedef uint32_t u32;

__device__ __forceinline__ uint16_t f2bu(float f) {
  uint32_t u = __float_as_uint(f);
  u += 0x7fffu + ((u >> 16) & 1u);
  return (uint16_t)(u >> 16);
}

__device__ __forceinline__ float bu2f(uint16_t x) {
  return __uint_as_float(((uint32_t)x) << 16);
}

__device__ __forceinline__ u32 pkbf(float a, float b) {
  union { __bf16 h[2]; u32 u; } t;
  t.h[0] = (__bf16)a; t.h[1] = (__bf16)b;
  return t.u;
}

__device__ __forceinline__ bf16x8 mkfrag(u32 a, u32 b, u32 c, u32 d) {
  union { u32 u[4]; bf16x8 v; } t;
  t.u[0] = a; t.u[1] = b; t.u[2] = c; t.u[3] = d;
  return t.v;
}

__device__ __forceinline__ void gload_lds16(const void* g, void* l) {
  __builtin_amdgcn_global_load_lds(
      (const __attribute__((address_space(1))) void*)g,
      (__attribute__((address_space(3))) void*)l, 16, 0, 0);
}

// ---------------- cast fp32 -> bf16 (vectorized) ----------------
__global__ void cast_f32_bf16(const float* __restrict__ in, uint16_t* __restrict__ out, int n4) {
  int i = blockIdx.x * blockDim.x + threadIdx.x;
  int stride = gridDim.x * blockDim.x;
  for (; i < n4; i += stride) {
    float4 v = ((const float4*)in)[i];
    ushort4 o;
    o.x = f2bu(v.x); o.y = f2bu(v.y); o.z = f2bu(v.z); o.w = f2bu(v.w);
    ((ushort4*)out)[i] = o;
  }
}

// ---------------- transpose + cast: W[K][N] f32 -> Wt[N][K] bf16 ----------------
__global__ void transpose_cast(const float* __restrict__ w, uint16_t* __restrict__ wt, int K, int N) {
  __shared__ float tile[32][33];
  int kb = blockIdx.x * 32, nb = blockIdx.y * 32;
  int tx = threadIdx.x & 31, ty = threadIdx.x >> 5;
  #pragma unroll
  for (int r = ty; r < 32; r += 8) tile[r][tx] = w[(size_t)(kb + r) * N + nb + tx];
  __syncthreads();
  #pragma unroll
  for (int r = ty; r < 32; r += 8) wt[(size_t)(nb + r) * K + kb + tx] = f2bu(tile[tx][r]);
}

// ---------------- QKV GEMM: scatter Q(pre-scaled)/K -> [B,H,T,Dh], V -> V^T [B,H,Dh,T] ----
__global__ __launch_bounds__(256) void gemm_qkv(
    const uint16_t* __restrict__ A, const uint16_t* __restrict__ Bt,
    const float* __restrict__ bias,
    uint16_t* __restrict__ q, uint16_t* __restrict__ k, uint16_t* __restrict__ v,
    int N, int K) {
  __shared__ uint16_t As[128 * 32];
  __shared__ uint16_t Bs[128 * 32];
  int tid = threadIdx.x;
  int w = tid >> 6, l = tid & 63;
  int lg = l >> 4, lr = l & 15;
  int mb = blockIdx.x * 128, nb = blockIdx.y * 128;
  int wr = (w >> 1) * 64, wc = (w & 1) * 64;
  f32x4 acc[4][4] = {};
  int srow = tid >> 2, scol = (tid & 3) * 8;
  const uint16_t* Ag = A + (size_t)(mb + srow) * K + scol;
  const uint16_t* Bg = Bt + (size_t)(nb + srow) * K + scol;
  char* AsB = (char*)As + (size_t)w * 1024;
  char* BsB = (char*)Bs + (size_t)w * 1024;
  size_t rowskip = (size_t)64 * K;
  for (int kb = 0; kb < K; kb += 32) {
    __syncthreads();
    gload_lds16(Ag + kb, AsB);
    gload_lds16(Ag + kb + rowskip, AsB + 4096);
    gload_lds16(Bg + kb, BsB);
    gload_lds16(Bg + kb + rowskip, BsB + 4096);
    __syncthreads();
    bf16x8 af[4], bfr[4];
    #pragma unroll
    for (int i = 0; i < 4; ++i)
      af[i] = *(const bf16x8_a*)(const void*)(As + (wr + i * 16 + lr) * 32 + lg * 8);
    #pragma unroll
    for (int i = 0; i < 4; ++i)
      bfr[i] = *(const bf16x8_a*)(const void*)(Bs + (wc + i * 16 + lr) * 32 + lg * 8);
    #pragma unroll
    for (int mi = 0; mi < 4; ++mi)
      #pragma unroll
      for (int ni = 0; ni < 4; ++ni)
        acc[mi][ni] = __builtin_amdgcn_mfma_f32_16x16x32_bf16(af[mi], bfr[ni], acc[mi][ni], 0, 0, 0);
  }
  #pragma unroll
  for (int mi = 0; mi < 4; ++mi) {
    #pragma unroll
    for (int ni = 0; ni < 4; ++ni) {
      int gm0 = mb + wr + mi * 16 + lg * 4;
      int gn = nb + wc + ni * 16 + lr;
      int which = gn / CDIM;
      int cc = gn - which * CDIM;
      int hh = cc >> 6, d = cc & 63;
      float bs = bias[gn];
      if (which == 2) {
        int b0 = gm0 >> 12, t0 = gm0 & 4095;
        ushort4 pk;
        pk.x = f2bu(acc[mi][ni][0] + bs);
        pk.y = f2bu(acc[mi][ni][1] + bs);
        pk.z = f2bu(acc[mi][ni][2] + bs);
        pk.w = f2bu(acc[mi][ni][3] + bs);
        *(ushort4*)&v[(((size_t)(b0 * NH + hh)) * DH + d) * TSEQ + t0] = pk;
      } else {
        uint16_t* dst = which ? k : q;
        float sc = which ? 1.0f : 0.1803368801111204f;  // 0.125 * log2(e)
        #pragma unroll
        for (int j = 0; j < 4; ++j) {
          int gm = gm0 + j;
          int bb = gm >> 12, t = gm & 4095;
          float val = (acc[mi][ni][j] + bs) * sc;
          dst[(((size_t)(bb * NH + hh)) * TSEQ + t) * DH + d] = f2bu(val);
        }
      }
    }
  }
}

// ---------------- out-proj GEMM: BM=128, BN=64 -> grid 64x12 = 768 blocks ----
__global__ __launch_bounds__(256) void gemm_out(
    const uint16_t* __restrict__ A, const uint16_t* __restrict__ Bt,
    const float* __restrict__ bias, float* __restrict__ outf, int N, int K) {
  __shared__ uint16_t As[128 * 32];
  __shared__ uint16_t Bs[64 * 32];
  int tid = threadIdx.x;
  int w = tid >> 6, l = tid & 63;
  int lg = l >> 4, lr = l & 15;
  int mb = blockIdx.x * 128, nb = blockIdx.y * 64;
  int wr = w * 32;
  f32x4 acc[2][4] = {};
  int srow = tid >> 2, scol = (tid & 3) * 8;
  const uint16_t* Ag = A + (size_t)(mb + srow) * K + scol;
  const uint16_t* Bg = Bt + (size_t)(nb + srow) * K + scol;
  char* AsB = (char*)As + (size_t)w * 1024;
  char* BsB = (char*)Bs + (size_t)w * 1024;
  size_t rowskip = (size_t)64 * K;
  for (int kb = 0; kb < K; kb += 32) {
    __syncthreads();
    gload_lds16(Ag + kb, AsB);
    gload_lds16(Ag + kb + rowskip, AsB + 4096);
    gload_lds16(Bg + kb, BsB);
    __syncthreads();
    bf16x8 af[2], bfr[4];
    #pragma unroll
    for (int i = 0; i < 2; ++i)
      af[i] = *(const bf16x8_a*)(const void*)(As + (wr + i * 16 + lr) * 32 + lg * 8);
    #pragma unroll
    for (int i = 0; i < 4; ++i)
      bfr[i] = *(const bf16x8_a*)(const void*)(Bs + (i * 16 + lr) * 32 + lg * 8);
    #pragma unroll
    for (int mi = 0; mi < 2; ++mi)
      #pragma unroll
      for (int ni = 0; ni < 4; ++ni)
        acc[mi][ni] = __builtin_amdgcn_mfma_f32_16x16x32_bf16(af[mi], bfr[ni], acc[mi][ni], 0, 0, 0);
  }
  #pragma unroll
  for (int mi = 0; mi < 2; ++mi) {
    #pragma unroll
    for (int ni = 0; ni < 4; ++ni) {
      #pragma unroll
      for (int j = 0; j < 4; ++j) {
        int gm = mb + wr + mi * 16 + lg * 4 + j;
        int gn = nb + ni * 16 + lr;
        outf[(size_t)gm * N + gn] = acc[mi][ni][j] + bias[gn];
      }
    }
  }
}

// lsum slot base within [64] per qt (multi-chunk qt only: 11..31)
__device__ __forceinline__ int lbase_qt(int qt) {
  return (qt < 22) ? (qt - 11) * 2 : 22 + (qt - 22) * 3;
}
// Pbuf extra-chunk slot base within [31] per qt
__device__ __forceinline__ int ebase_qt(int qt) {
  return (qt < 22) ? (qt - 11) : 11 + (qt - 22) * 2;
}

// ---------------- flash attention: in-register P (r17) + double-buffered K/V (32KB) -----
// r17's permuted-K-row QK^T keeps P entirely in registers (no P LDS tile), freeing LDS so
// K/V double-buffering fits in 32KB -> 5 blocks/CU (vs r15's 40KB/4 that regressed).
// Loop: STAGE(t+1) into buf^1 issues BEFORE compute on buf[cur]; single barrier per tile
// drains the prefetch after compute has covered its latency.
// QK^T MFMA ni loads K rows f_ni(r)=8(r>>2)+(r&3)+{0,4,32,36} => lane (lg,lr) holds
// S[q=lr][k=8lg+j+off_ni]; after exp2+pack registers ARE the PV A-fragments.
// Staging swizzle g(row) = (row&7) ^ 4*((row>>3)&1) keeps all reads 2-way-free.
// Work decomposition (r14): qt<=10 direct; 11..21: 2 chunks; 22..31: 3. Max chain 22.
__global__ __launch_bounds__(256) void attn_part(
    const uint16_t* __restrict__ Q, const uint16_t* __restrict__ K,
    const uint16_t* __restrict__ Vt, uint16_t* __restrict__ O,
    uint16_t* __restrict__ Pbuf, float* __restrict__ Pl) {
  int gid = blockIdx.x;
  int widx = gid / 24, bh = gid - widx * 24;
  int qt, c, nch;
  if (widx < 30) { qt = 31 - widx / 3; c = widx % 3; nch = 3; }
  else if (widx < 52) { int u = widx - 30; qt = 21 - (u >> 1); c = u & 1; nch = 2; }
  else { qt = 62 - widx; c = 0; nch = 1; }
  int ntile = 2 * qt + 2;
  int L = (ntile + nch - 1) / nch;
  int t0 = c * L;
  int t1 = min(ntile - 1, t0 + L - 1);

  int b = bh / NH, hd = bh - b * NH;
  size_t base = (size_t)bh * TSEQ * DH;
  int tid = threadIdx.x, w = tid >> 6, lane = tid & 63;
  int lg = lane >> 4, lr = lane & 15;
  __shared__ __align__(16) uint16_t Ks[2][64 * 64];
  __shared__ __align__(16) uint16_t Vs[2][64 * 64];
  // staging: pre-swizzled global source, linear LDS dest; g(row) = (row&7) ^ 4*((row>>3)&1)
  int srow = tid >> 3;
  int schunk = (tid & 7) ^ (srow & 7) ^ (((srow >> 3) & 1) << 2);
  const uint16_t* Kg0 = K + base + (size_t)srow * DH + schunk * 8;
  const uint16_t* Vg0 = Vt + base + (size_t)srow * TSEQ + schunk * 8;

  // per-lane read constants
  int rb = ((lr >> 2) << 3) | (lr & 3);                 // K base row (ni=0)
  int ck0 = lg ^ (lr & 3) ^ (((lr >> 2) & 1) << 2);     // K phys chunk (ni even)
  int cv0 = lg ^ (lr & 7) ^ (((lr >> 3) & 1) << 2);     // V phys chunk (vf0)

  int qb = qt * 128;
  int qgA = qb + w * 16 + lr;
  int qgB = qgA + 64;
  bf16x8 qA0 = *(const bf16x8_a*)(const void*)(Q + base + (size_t)qgA * DH + lg * 8);
  bf16x8 qA1 = *(const bf16x8_a*)(const void*)(Q + base + (size_t)qgA * DH + 32 + lg * 8);
  bf16x8 qB0 = *(const bf16x8_a*)(const void*)(Q + base + (size_t)qgB * DH + lg * 8);
  bf16x8 qB1 = *(const bf16x8_a*)(const void*)(Q + base + (size_t)qgB * DH + 32 + lg * 8);
  f32x4 oA[4] = {}, oB[4] = {};
  float lA = 0.f, lB = 0.f;
  int lg4 = lg * 4, lg8 = lg * 8;

#define STAGE(bufi, tv) do { \
    char* kd_ = (char*)Ks[bufi] + w * 1024; \
    char* vd_ = (char*)Vs[bufi] + w * 1024; \
    const uint16_t* kg_ = Kg0 + (size_t)(tv) * (64 * DH); \
    const uint16_t* vg_ = Vg0 + (size_t)(tv) * 64; \
    gload_lds16(kg_,           kd_); \
    gload_lds16(kg_ + 32 * DH, kd_ + 4096); \
    gload_lds16(vg_,                     vd_); \
    gload_lds16(vg_ + (size_t)32 * TSEQ, vd_ + 4096); \
  } while (0)

  STAGE(0, t0);
  __syncthreads();                      // drain stage t0
  int cur = 0;
  for (int t = t0; t <= t1; ++t) {
    if (t + 1 <= t1) STAGE(cur ^ 1, t + 1);   // prefetch flies under this tile's compute
    const char* Kc = (const char*)Ks[cur];
    const char* Vc = (const char*)Vs[cur];
    bool doA = (t <= 2 * qt);
    int kb0 = t * 64;
    // ---- QK^T with permuted K rows: s[ni][j] = S[q][k = 8lg + j + off_ni] ----
    f32x4 sA[4], sB[4];
    __builtin_amdgcn_s_setprio(1);
    #pragma unroll
    for (int ni = 0; ni < 4; ++ni) {
      int row = rb + ((ni & 1) << 2) + ((ni >> 1) << 5);
      int ch = ck0 ^ ((ni & 1) << 2);
      const char* kbp = Kc + row * 128;
      bf16x8 kf0 = *(const bf16x8_a*)(kbp + ch * 16);
      bf16x8 kf1 = *(const bf16x8_a*)(kbp + (ch ^ 4) * 16);
      f32x4 s = {};
      s = __builtin_amdgcn_mfma_f32_16x16x32_bf16(kf0, qB0, s, 0, 0, 0);
      s = __builtin_amdgcn_mfma_f32_16x16x32_bf16(kf1, qB1, s, 0, 0, 0);
      sB[ni] = s;
      if (doA) {
        f32x4 sa = {};
        sa = __builtin_amdgcn_mfma_f32_16x16x32_bf16(kf0, qA0, sa, 0, 0, 0);
        sa = __builtin_amdgcn_mfma_f32_16x16x32_bf16(kf1, qA1, sa, 0, 0, 0);
        sA[ni] = sa;
      }
    }
    __builtin_amdgcn_s_setprio(0);
    // ---- substep A: mask + exp2 + in-register pack ----
    bf16x8 pfA0, pfA1;
    if (doA) {
      if (t == 2 * qt) {
        int thr = qgA - kb0 - lg8;      // keep off_ni + j <= thr
        #pragma unroll
        for (int ni = 0; ni < 4; ++ni) {
          int off = ((ni & 1) << 2) + ((ni >> 1) << 5);
          #pragma unroll
          for (int j = 0; j < 4; ++j)
            sA[ni][j] = (off + j <= thr) ? sA[ni][j] : -1e30f;
        }
      }
      u32 ca[8];
      #pragma unroll
      for (int ni = 0; ni < 4; ++ni) {
        float p0 = __builtin_amdgcn_exp2f(sA[ni][0]);
        float p1 = __builtin_amdgcn_exp2f(sA[ni][1]);
        float p2 = __builtin_amdgcn_exp2f(sA[ni][2]);
        float p3 = __builtin_amdgcn_exp2f(sA[ni][3]);
        lA += (p0 + p1) + (p2 + p3);
        ca[2 * ni] = pkbf(p0, p1);
        ca[2 * ni + 1] = pkbf(p2, p3);
      }
      pfA0 = mkfrag(ca[0], ca[1], ca[2], ca[3]);   // k = 8lg..8lg+7
      pfA1 = mkfrag(ca[4], ca[5], ca[6], ca[7]);   // k = 32+8lg..+7
    }
    // ---- substep B: mask + exp2 + in-register pack ----
    bf16x8 pfB0, pfB1;
    {
      if (t == 2 * qt + 1) {
        int thr = qgB - kb0 - lg8;
        #pragma unroll
        for (int ni = 0; ni < 4; ++ni) {
          int off = ((ni & 1) << 2) + ((ni >> 1) << 5);
          #pragma unroll
          for (int j = 0; j < 4; ++j)
            sB[ni][j] = (off + j <= thr) ? sB[ni][j] : -1e30f;
        }
      }
      u32 cb[8];
      #pragma unroll
      for (int ni = 0; ni < 4; ++ni) {
        float p0 = __builtin_amdgcn_exp2f(sB[ni][0]);
        float p1 = __builtin_amdgcn_exp2f(sB[ni][1]);
        float p2 = __builtin_amdgcn_exp2f(sB[ni][2]);
        float p3 = __builtin_amdgcn_exp2f(sB[ni][3]);
        lB += (p0 + p1) + (p2 + p3);
        cb[2 * ni] = pkbf(p0, p1);
        cb[2 * ni + 1] = pkbf(p2, p3);
      }
      pfB0 = mkfrag(cb[0], cb[1], cb[2], cb[3]);
      pfB1 = mkfrag(cb[4], cb[5], cb[6], cb[7]);
    }
    // ---- PV: V-frag pair feeds both substeps ----
    __builtin_amdgcn_s_setprio(1);
    #pragma unroll
    for (int nd = 0; nd < 4; ++nd) {
      const char* vb = Vc + (nd * 16 + lr) * 128;
      bf16x8 vf0 = *(const bf16x8_a*)(vb + cv0 * 16);
      bf16x8 vf1 = *(const bf16x8_a*)(vb + (cv0 ^ 4) * 16);
      oB[nd] = __builtin_amdgcn_mfma_f32_16x16x32_bf16(pfB0, vf0, oB[nd], 0, 0, 0);
      oB[nd] = __builtin_amdgcn_mfma_f32_16x16x32_bf16(pfB1, vf1, oB[nd], 0, 0, 0);
      if (doA) {
        oA[nd] = __builtin_amdgcn_mfma_f32_16x16x32_bf16(pfA0, vf0, oA[nd], 0, 0, 0);
        oA[nd] = __builtin_amdgcn_mfma_f32_16x16x32_bf16(pfA1, vf1, oA[nd], 0, 0, 0);
      }
    }
    __builtin_amdgcn_s_setprio(0);
    __syncthreads();                    // drains prefetch; all waves done with buf[cur]
    cur ^= 1;
  }
#undef STAGE

  lA += __shfl_xor(lA, 16, 64); lA += __shfl_xor(lA, 32, 64);
  lB += __shfl_xor(lB, 16, 64); lB += __shfl_xor(lB, 32, 64);
  if (nch == 1) {
    float riA = 1.0f / lA, riB = 1.0f / lB;
    #pragma unroll
    for (int j = 0; j < 4; ++j) {
      float rvA = __shfl(riA, (lane & 48) | (lg4 + j), 64);
      float rvB = __shfl(riB, (lane & 48) | (lg4 + j), 64);
      int tA = qb + w * 16 + lg4 + j;
      size_t pA = (size_t)(b * TSEQ + tA) * CDIM + hd * DH + lr;
      size_t pB = pA + (size_t)64 * CDIM;
      #pragma unroll
      for (int nd = 0; nd < 4; ++nd) {
        O[pA + nd * 16] = f2bu(oA[nd][j] * rvA);
        O[pB + nd * 16] = f2bu(oB[nd][j] * rvB);
      }
    }
  } else {
    float* pl = Pl + (size_t)(bh * 64 + lbase_qt(qt) + c) * 128;
    if (lane < 16) {
      pl[w * 16 + lane] = lA;
      pl[64 + w * 16 + lane] = lB;
    }
    if (c == 0) {
      #pragma unroll
      for (int j = 0; j < 4; ++j) {
        int tA = qb + w * 16 + lg4 + j;
        size_t pA = (size_t)(b * TSEQ + tA) * CDIM + hd * DH + lr;
        size_t pB = pA + (size_t)64 * CDIM;
        #pragma unroll
        for (int nd = 0; nd < 4; ++nd) {
          O[pA + nd * 16] = f2bu(oA[nd][j]);
          O[pB + nd * 16] = f2bu(oB[nd][j]);
        }
      }
    } else {
      uint16_t* Pb = Pbuf + (size_t)(bh * 31 + ebase_qt(qt) + (c - 1)) * 8192;
      #pragma unroll
      for (int j = 0; j < 4; ++j) {
        int qlA = w * 16 + lg4 + j;
        #pragma unroll
        for (int nd = 0; nd < 4; ++nd) {
          Pb[qlA * 64 + nd * 16 + lr] = f2bu(oA[nd][j]);
          Pb[(64 + qlA) * 64 + nd * 16 + lr] = f2bu(oB[nd][j]);
        }
      }
    }
  }
}

// ---------------- combine chunk partials in-place in Ob (vectorized ushort4) -------------
__global__ __launch_bounds__(256) void attn_reduce(
    const uint16_t* __restrict__ Pbuf, const float* __restrict__ Pl,
    uint16_t* __restrict__ O) {
  int rid = blockIdx.x;                // 0..503 = bh*21 + (qt-11)
  int bh = rid / 21, qt = 11 + (rid - bh * 21);
  int nch = (qt >= 22) ? 3 : 2;
  int b = bh / NH, hd = bh - b * NH;
  int tid = threadIdx.x;
  const float* pl = Pl + (size_t)(bh * 64 + lbase_qt(qt)) * 128;
  const uint16_t* pb = Pbuf + (size_t)(bh * 31 + ebase_qt(qt)) * 8192;
  #pragma unroll
  for (int it = 0; it < 8; ++it) {
    int idx = it * 256 + tid;          // 0..2047 = q*16 + dq
    int q = idx >> 4, dq = idx & 15;
    float lsum = pl[q] + pl[128 + q];
    if (nch == 3) lsum += pl[256 + q];
    float linv = 1.0f / lsum;
    int t = qt * 128 + q;
    size_t po = (size_t)(b * TSEQ + t) * CDIM + hd * DH + dq * 4;
    ushort4 ov = *(const ushort4*)&O[po];
    ushort4 pv = *(const ushort4*)&pb[q * 64 + dq * 4];
    float s0 = bu2f(ov.x) + bu2f(pv.x);
    float s1 = bu2f(ov.y) + bu2f(pv.y);
    float s2 = bu2f(ov.z) + bu2f(pv.z);
    float s3 = bu2f(ov.w) + bu2f(pv.w);
    if (nch == 3) {
      ushort4 pv2 = *(const ushort4*)&pb[8192 + q * 64 + dq * 4];
      s0 += bu2f(pv2.x); s1 += bu2f(pv2.y); s2 += bu2f(pv2.z); s3 += bu2f(pv2.w);
    }
    ushort4 o;
    o.x = f2bu(s0 * linv); o.y = f2bu(s1 * linv);
    o.z = f2bu(s2 * linv); o.w = f2bu(s3 * linv);
    *(ushort4*)&O[po] = o;
  }
}

extern "C" void kernel_launch(void* const* d_in, const int* in_sizes, int n_in,
                              void* d_out, int out_size, void* d_ws, size_t ws_size,
                              hipStream_t stream) {
  const float* x    = (const float*)d_in[0];
  const float* Wqkv = (const float*)d_in[1];
  const float* bqkv = (const float*)d_in[2];
  const float* Wout = (const float*)d_in[3];
  const float* bout = (const float*)d_in[4];
  float* out = (float*)d_out;
  char* ws = (char*)d_ws;

  uint16_t* Xb    = (uint16_t*)(ws + 0);          // 8192*768*2   = 12,582,912
  uint16_t* Wqkvt = (uint16_t*)(ws + 12582912);   // 2304*768*2   =  3,538,944
  uint16_t* Woutt = (uint16_t*)(ws + 16121856);   // 768*768*2    =  1,179,648
  uint16_t* Qb    = (uint16_t*)(ws + 17301504);   // 12,582,912 (pre-scaled)
  uint16_t* Kb    = (uint16_t*)(ws + 29884416);   // 12,582,912
  uint16_t* Vtb   = (uint16_t*)(ws + 42467328);   // 12,582,912 (V^T [B,H,Dh,T])
  uint16_t* Ob    = (uint16_t*)(ws + 55050240);   // 12,582,912 (end 67,633,152)
  // dead after gemm_qkv: reuse as split-KV partial buffers (no extra ws)
  uint16_t* Pbuf  = Xb;                           // [24*31][128][64] bf16 = 12,189,696
  float*    Pl    = (float*)Wqkvt;                // [24*64][128] f32 = 786,432

  cast_f32_bf16<<<2048, 256, 0, stream>>>(x, Xb, (MROWS * CDIM) / 4);
  transpose_cast<<<dim3(24, 72), 256, 0, stream>>>(Wqkv, Wqkvt, 768, 2304);
  transpose_cast<<<dim3(24, 24), 256, 0, stream>>>(Wout, Woutt, 768, 768);
  gemm_qkv<<<dim3(64, 18), 256, 0, stream>>>(Xb, Wqkvt, bqkv, Qb, Kb, Vtb, 2304, 768);
  attn_part<<<1512, 256, 0, stream>>>(Qb, Kb, Vtb, Ob, Pbuf, Pl);
  attn_reduce<<<504, 256, 0, stream>>>(Pbuf, Pl, Ob);
  gemm_out<<<dim3(64, 12), 256, 0, stream>>>(Ob, Woutt, bout, out, 768, 768);
}

// Round 19
// 169.837 us; speedup vs baseline: 1.0515x; 1.0515x over previous
//
#include <hip/hip_runtime.h>
#include <hip/hip_bf16.h>
#include <cstdint>

#define NH 12
#define DH 64
#define TSEQ 4096
#define BATCH 2
#define CDIM 768
#define MROWS (BATCH*TSEQ)

typedef __bf16 bf16x8 __attribute__((ext_vector_type(8)));
typedef __bf16 bf16x4 __attribute__((ext_vector_type(4)));
typedef bf16x8 bf16x8_a __attribute__((may_alias));
typedef bf16x4 bf16x4_a __attribute__((may_alias));
typedef float f32x4 __attribute__((ext_vector_type(4)));

__device__ __forceinline__ uint16_t f2bu(float f) {
  uint32_t u = __float_as_uint(f);
  u += 0x7fffu + ((u >> 16) & 1u);
  return (uint16_t)(u >> 16);
}

__device__ __forceinline__ float bu2f(uint16_t x) {
  return __uint_as_float(((uint32_t)x) << 16);
}

__device__ __forceinline__ void gload_lds16(const void* g, void* l) {
  __builtin_amdgcn_global_load_lds(
      (const __attribute__((address_space(1))) void*)g,
      (__attribute__((address_space(3))) void*)l, 16, 0, 0);
}

// ---------------- cast fp32 -> bf16 (vectorized) ----------------
__global__ void cast_f32_bf16(const float* __restrict__ in, uint16_t* __restrict__ out, int n4) {
  int i = blockIdx.x * blockDim.x + threadIdx.x;
  int stride = gridDim.x * blockDim.x;
  for (; i < n4; i += stride) {
    float4 v = ((const float4*)in)[i];
    ushort4 o;
    o.x = f2bu(v.x); o.y = f2bu(v.y); o.z = f2bu(v.z); o.w = f2bu(v.w);
    ((ushort4*)out)[i] = o;
  }
}

// ---------------- transpose + cast: W[K][N] f32 -> Wt[N][K] bf16 ----------------
__global__ void transpose_cast(const float* __restrict__ w, uint16_t* __restrict__ wt, int K, int N) {
  __shared__ float tile[32][33];
  int kb = blockIdx.x * 32, nb = blockIdx.y * 32;
  int tx = threadIdx.x & 31, ty = threadIdx.x >> 5;
  #pragma unroll
  for (int r = ty; r < 32; r += 8) tile[r][tx] = w[(size_t)(kb + r) * N + nb + tx];
  __syncthreads();
  #pragma unroll
  for (int r = ty; r < 32; r += 8) wt[(size_t)(nb + r) * K + kb + tx] = f2bu(tile[tx][r]);
}

// ---------------- QKV GEMM (BK=64, swizzled LDS): Q(pre-scaled)/K -> [B,H,T,Dh], V^T ----
// LDS tiles [128][64] bf16, chunk c of row r stored at slot c^(r&7) (attn-verified,
// conflict-free reads). 12 K-iterations, 32 MFMA per barrier-pair.
__global__ __launch_bounds__(256) void gemm_qkv(
    const uint16_t* __restrict__ A, const uint16_t* __restrict__ Bt,
    const float* __restrict__ bias,
    uint16_t* __restrict__ q, uint16_t* __restrict__ k, uint16_t* __restrict__ v,
    int N, int K) {
  __shared__ __align__(16) uint16_t As[128 * 64];
  __shared__ __align__(16) uint16_t Bs[128 * 64];
  int tid = threadIdx.x;
  int w = tid >> 6, l = tid & 63;
  int lg = l >> 4, lr = l & 15;
  int mb = blockIdx.x * 128, nb = blockIdx.y * 128;
  int wr = (w >> 1) * 64, wc = (w & 1) * 64;
  f32x4 acc[4][4] = {};
  int srow = tid >> 3;                       // 0..31
  int schunk = (tid & 7) ^ (srow & 7);       // pre-swizzled source chunk
  const uint16_t* Ag = A + (size_t)(mb + srow) * K + schunk * 8;
  const uint16_t* Bg = Bt + (size_t)(nb + srow) * K + schunk * 8;
  char* AsB = (char*)As + (size_t)w * 1024;
  char* BsB = (char*)Bs + (size_t)w * 1024;
  size_t rowskip = (size_t)32 * K;
  for (int kb = 0; kb < K; kb += 64) {
    __syncthreads();
    #pragma unroll
    for (int r = 0; r < 4; ++r) {
      gload_lds16(Ag + kb + (size_t)r * rowskip, AsB + r * 4096);
      gload_lds16(Bg + kb + (size_t)r * rowskip, BsB + r * 4096);
    }
    __syncthreads();
    #pragma unroll
    for (int h = 0; h < 2; ++h) {
      bf16x8 af[4], bfr[4];
      #pragma unroll
      for (int i = 0; i < 4; ++i) {
        int rowA = wr + i * 16 + lr;
        af[i] = *(const bf16x8_a*)((const char*)As + rowA * 128 + (((lg + 4 * h) ^ (rowA & 7)) << 4));
        int rowB = wc + i * 16 + lr;
        bfr[i] = *(const bf16x8_a*)((const char*)Bs + rowB * 128 + (((lg + 4 * h) ^ (rowB & 7)) << 4));
      }
      #pragma unroll
      for (int mi = 0; mi < 4; ++mi)
        #pragma unroll
        for (int ni = 0; ni < 4; ++ni)
          acc[mi][ni] = __builtin_amdgcn_mfma_f32_16x16x32_bf16(af[mi], bfr[ni], acc[mi][ni], 0, 0, 0);
    }
  }
  #pragma unroll
  for (int mi = 0; mi < 4; ++mi) {
    #pragma unroll
    for (int ni = 0; ni < 4; ++ni) {
      int gm0 = mb + wr + mi * 16 + lg * 4;
      int gn = nb + wc + ni * 16 + lr;
      int which = gn / CDIM;
      int cc = gn - which * CDIM;
      int hh = cc >> 6, d = cc & 63;
      float bs = bias[gn];
      if (which == 2) {
        int b0 = gm0 >> 12, t0 = gm0 & 4095;
        ushort4 pk;
        pk.x = f2bu(acc[mi][ni][0] + bs);
        pk.y = f2bu(acc[mi][ni][1] + bs);
        pk.z = f2bu(acc[mi][ni][2] + bs);
        pk.w = f2bu(acc[mi][ni][3] + bs);
        *(ushort4*)&v[(((size_t)(b0 * NH + hh)) * DH + d) * TSEQ + t0] = pk;
      } else {
        uint16_t* dst = which ? k : q;
        float sc = which ? 1.0f : 0.1803368801111204f;  // 0.125 * log2(e)
        #pragma unroll
        for (int j = 0; j < 4; ++j) {
          int gm = gm0 + j;
          int bb = gm >> 12, t = gm & 4095;
          float val = (acc[mi][ni][j] + bs) * sc;
          dst[(((size_t)(bb * NH + hh)) * TSEQ + t) * DH + d] = f2bu(val);
        }
      }
    }
  }
}

// ---------------- out-proj GEMM (BK=64, swizzled LDS): BM=128, BN=64, grid 64x12 ----
__global__ __launch_bounds__(256) void gemm_out(
    const uint16_t* __restrict__ A, const uint16_t* __restrict__ Bt,
    const float* __restrict__ bias, float* __restrict__ outf, int N, int K) {
  __shared__ __align__(16) uint16_t As[128 * 64];
  __shared__ __align__(16) uint16_t Bs[64 * 64];
  int tid = threadIdx.x;
  int w = tid >> 6, l = tid & 63;
  int lg = l >> 4, lr = l & 15;
  int mb = blockIdx.x * 128, nb = blockIdx.y * 64;
  int wr = w * 32;
  f32x4 acc[2][4] = {};
  int srow = tid >> 3;
  int schunk = (tid & 7) ^ (srow & 7);
  const uint16_t* Ag = A + (size_t)(mb + srow) * K + schunk * 8;
  const uint16_t* Bg = Bt + (size_t)(nb + srow) * K + schunk * 8;
  char* AsB = (char*)As + (size_t)w * 1024;
  char* BsB = (char*)Bs + (size_t)w * 1024;
  size_t rowskip = (size_t)32 * K;
  for (int kb = 0; kb < K; kb += 64) {
    __syncthreads();
    #pragma unroll
    for (int r = 0; r < 4; ++r)
      gload_lds16(Ag + kb + (size_t)r * rowskip, AsB + r * 4096);
    #pragma unroll
    for (int r = 0; r < 2; ++r)
      gload_lds16(Bg + kb + (size_t)r * rowskip, BsB + r * 4096);
    __syncthreads();
    #pragma unroll
    for (int h = 0; h < 2; ++h) {
      bf16x8 af[2], bfr[4];
      #pragma unroll
      for (int i = 0; i < 2; ++i) {
        int rowA = wr + i * 16 + lr;
        af[i] = *(const bf16x8_a*)((const char*)As + rowA * 128 + (((lg + 4 * h) ^ (rowA & 7)) << 4));
      }
      #pragma unroll
      for (int i = 0; i < 4; ++i) {
        int rowB = i * 16 + lr;
        bfr[i] = *(const bf16x8_a*)((const char*)Bs + rowB * 128 + (((lg + 4 * h) ^ (rowB & 7)) << 4));
      }
      #pragma unroll
      for (int mi = 0; mi < 2; ++mi)
        #pragma unroll
        for (int ni = 0; ni < 4; ++ni)
          acc[mi][ni] = __builtin_amdgcn_mfma_f32_16x16x32_bf16(af[mi], bfr[ni], acc[mi][ni], 0, 0, 0);
    }
  }
  #pragma unroll
  for (int mi = 0; mi < 2; ++mi) {
    #pragma unroll
    for (int ni = 0; ni < 4; ++ni) {
      #pragma unroll
      for (int j = 0; j < 4; ++j) {
        int gm = mb + wr + mi * 16 + lg * 4 + j;
        int gn = nb + ni * 16 + lr;
        outf[(size_t)gm * N + gn] = acc[mi][ni][j] + bias[gn];
      }
    }
  }
}

// lsum slot base within [64] per qt (multi-chunk qt only: 11..31)
__device__ __forceinline__ int lbase_qt(int qt) {
  return (qt < 22) ? (qt - 11) * 2 : 22 + (qt - 22) * 3;
}
// Pbuf extra-chunk slot base within [31] per qt
__device__ __forceinline__ int ebase_qt(int qt) {
  return (qt < 22) ? (qt - 11) : 11 + (qt - 22) * 2;
}

// ---------------- flash attention (r16-exact best: 89.5 µs) ----------------
// Merged A/B substeps, 24KB single-buffer swizzled LDS (6 blocks/CU, all 1512 resident),
// uniform-chunk split-KV (qt<=10 direct; 11..21: 2; 22..31: 3; max chain 22 tiles).
// Fixed-ref softmax exp2-domain, swapped QK^T, K/V frags read once per tile,
// P via per-wave swizzled LDS roundtrip.
__global__ __launch_bounds__(256) void attn_part(
    const uint16_t* __restrict__ Q, const uint16_t* __restrict__ K,
    const uint16_t* __restrict__ Vt, uint16_t* __restrict__ O,
    uint16_t* __restrict__ Pbuf, float* __restrict__ Pl) {
  int gid = blockIdx.x;
  int widx = gid / 24, bh = gid - widx * 24;
  int qt, c, nch;
  if (widx < 30) { qt = 31 - widx / 3; c = widx % 3; nch = 3; }
  else if (widx < 52) { int u = widx - 30; qt = 21 - (u >> 1); c = u & 1; nch = 2; }
  else { qt = 62 - widx; c = 0; nch = 1; }
  int ntile = 2 * qt + 2;
  int L = (ntile + nch - 1) / nch;
  int t0 = c * L;
  int t1 = min(ntile - 1, t0 + L - 1);

  int b = bh / NH, hd = bh - b * NH;
  size_t base = (size_t)bh * TSEQ * DH;
  int tid = threadIdx.x, w = tid >> 6, lane = tid & 63;
  int lg = lane >> 4, lr = lane & 15;
  __shared__ __align__(16) uint16_t Ks[64 * 64];
  __shared__ __align__(16) uint16_t Vs[64 * 64];
  __shared__ uint16_t Ps[4][16 * 64];
  char* pw = (char*)Ps[w];
  int srow = tid >> 3;
  int schunk = (tid & 7) ^ (srow & 7);
  const uint16_t* Kg0 = K + base + (size_t)srow * DH + schunk * 8;
  const uint16_t* Vg0 = Vt + base + (size_t)srow * TSEQ + schunk * 8;
  char* KsB = (char*)Ks + w * 1024;
  char* VsB = (char*)Vs + w * 1024;
  int swzA = (lg ^ (lr & 7)) << 4;
  int swzB = swzA ^ 64;

  int qb = qt * 128;
  int qgA = qb + w * 16 + lr;
  int qgB = qgA + 64;
  bf16x8 qA0 = *(const bf16x8_a*)(const void*)(Q + base + (size_t)qgA * DH + lg * 8);
  bf16x8 qA1 = *(const bf16x8_a*)(const void*)(Q + base + (size_t)qgA * DH + 32 + lg * 8);
  bf16x8 qB0 = *(const bf16x8_a*)(const void*)(Q + base + (size_t)qgB * DH + lg * 8);
  bf16x8 qB1 = *(const bf16x8_a*)(const void*)(Q + base + (size_t)qgB * DH + 32 + lg * 8);
  f32x4 oA[4] = {}, oB[4] = {};
  float lA = 0.f, lB = 0.f;
  int lg4 = lg * 4;
  int pofs = (lg & 1) * 8;

  for (int t = t0; t <= t1; ++t) {
    __syncthreads();
    {
      const uint16_t* kg_ = Kg0 + (size_t)t * (64 * DH);
      const uint16_t* vg_ = Vg0 + (size_t)t * 64;
      gload_lds16(kg_,           KsB);
      gload_lds16(kg_ + 32 * DH, KsB + 4096);
      gload_lds16(vg_,                     VsB);
      gload_lds16(vg_ + (size_t)32 * TSEQ, VsB + 4096);
    }
    __syncthreads();
    bool doA = (t <= 2 * qt);
    int kb0 = t * 64;
    f32x4 sA[4], sB[4];
    __builtin_amdgcn_s_setprio(1);
    #pragma unroll
    for (int ni = 0; ni < 4; ++ni) {
      const char* kbp = (const char*)Ks + (ni * 16 + lr) * 128;
      bf16x8 kf0 = *(const bf16x8_a*)(kbp + swzA);
      bf16x8 kf1 = *(const bf16x8_a*)(kbp + swzB);
      f32x4 s = {};
      s = __builtin_amdgcn_mfma_f32_16x16x32_bf16(kf0, qB0, s, 0, 0, 0);
      s = __builtin_amdgcn_mfma_f32_16x16x32_bf16(kf1, qB1, s, 0, 0, 0);
      sB[ni] = s;
      if (doA) {
        f32x4 sa = {};
        sa = __builtin_amdgcn_mfma_f32_16x16x32_bf16(kf0, qA0, sa, 0, 0, 0);
        sa = __builtin_amdgcn_mfma_f32_16x16x32_bf16(kf1, qA1, sa, 0, 0, 0);
        sA[ni] = sa;
      }
    }
    __builtin_amdgcn_s_setprio(0);
    bf16x8 pfA0, pfA1;
    if (doA) {
      if (t == 2 * qt) {
        int thr = qgA - kb0 - lg4;
        #pragma unroll
        for (int ni = 0; ni < 4; ++ni)
          #pragma unroll
          for (int j = 0; j < 4; ++j)
            sA[ni][j] = (16 * ni + j <= thr) ? sA[ni][j] : -1e30f;
      }
      #pragma unroll
      for (int ni = 0; ni < 4; ++ni) {
        float p0 = __builtin_amdgcn_exp2f(sA[ni][0]);
        float p1 = __builtin_amdgcn_exp2f(sA[ni][1]);
        float p2 = __builtin_amdgcn_exp2f(sA[ni][2]);
        float p3 = __builtin_amdgcn_exp2f(sA[ni][3]);
        lA += (p0 + p1) + (p2 + p3);
        bf16x4 pk;
        pk[0] = (__bf16)p0; pk[1] = (__bf16)p1; pk[2] = (__bf16)p2; pk[3] = (__bf16)p3;
        int chunkc = (2 * ni + (lg >> 1)) ^ (lr & 7);
        *(bf16x4_a*)(pw + lr * 128 + chunkc * 16 + pofs) = pk;
      }
      pfA0 = *(const bf16x8_a*)(pw + lr * 128 + swzA);
      pfA1 = *(const bf16x8_a*)(pw + lr * 128 + swzB);
    }
    {
      if (t == 2 * qt + 1) {
        int thr = qgB - kb0 - lg4;
        #pragma unroll
        for (int ni = 0; ni < 4; ++ni)
          #pragma unroll
          for (int j = 0; j < 4; ++j)
            sB[ni][j] = (16 * ni + j <= thr) ? sB[ni][j] : -1e30f;
      }
      #pragma unroll
      for (int ni = 0; ni < 4; ++ni) {
        float p0 = __builtin_amdgcn_exp2f(sB[ni][0]);
        float p1 = __builtin_amdgcn_exp2f(sB[ni][1]);
        float p2 = __builtin_amdgcn_exp2f(sB[ni][2]);
        float p3 = __builtin_amdgcn_exp2f(sB[ni][3]);
        lB += (p0 + p1) + (p2 + p3);
        bf16x4 pk;
        pk[0] = (__bf16)p0; pk[1] = (__bf16)p1; pk[2] = (__bf16)p2; pk[3] = (__bf16)p3;
        int chunkc = (2 * ni + (lg >> 1)) ^ (lr & 7);
        *(bf16x4_a*)(pw + lr * 128 + chunkc * 16 + pofs) = pk;
      }
    }
    bf16x8 pfB0 = *(const bf16x8_a*)(pw + lr * 128 + swzA);
    bf16x8 pfB1 = *(const bf16x8_a*)(pw + lr * 128 + swzB);
    __builtin_amdgcn_s_setprio(1);
    #pragma unroll
    for (int nd = 0; nd < 4; ++nd) {
      const char* vb = (const char*)Vs + (nd * 16 + lr) * 128;
      bf16x8 vf0 = *(const bf16x8_a*)(vb + swzA);
      bf16x8 vf1 = *(const bf16x8_a*)(vb + swzB);
      oB[nd] = __builtin_amdgcn_mfma_f32_16x16x32_bf16(pfB0, vf0, oB[nd], 0, 0, 0);
      oB[nd] = __builtin_amdgcn_mfma_f32_16x16x32_bf16(pfB1, vf1, oB[nd], 0, 0, 0);
      if (doA) {
        oA[nd] = __builtin_amdgcn_mfma_f32_16x16x32_bf16(pfA0, vf0, oA[nd], 0, 0, 0);
        oA[nd] = __builtin_amdgcn_mfma_f32_16x16x32_bf16(pfA1, vf1, oA[nd], 0, 0, 0);
      }
    }
    __builtin_amdgcn_s_setprio(0);
  }

  lA += __shfl_xor(lA, 16, 64); lA += __shfl_xor(lA, 32, 64);
  lB += __shfl_xor(lB, 16, 64); lB += __shfl_xor(lB, 32, 64);
  if (nch == 1) {
    float riA = 1.0f / lA, riB = 1.0f / lB;
    #pragma unroll
    for (int j = 0; j < 4; ++j) {
      float rvA = __shfl(riA, (lane & 48) | (lg4 + j), 64);
      float rvB = __shfl(riB, (lane & 48) | (lg4 + j), 64);
      int tA = qb + w * 16 + lg4 + j;
      size_t pA = (size_t)(b * TSEQ + tA) * CDIM + hd * DH + lr;
      size_t pB = pA + (size_t)64 * CDIM;
      #pragma unroll
      for (int nd = 0; nd < 4; ++nd) {
        O[pA + nd * 16] = f2bu(oA[nd][j] * rvA);
        O[pB + nd * 16] = f2bu(oB[nd][j] * rvB);
      }
    }
  } else {
    float* pl = Pl + (size_t)(bh * 64 + lbase_qt(qt) + c) * 128;
    if (lane < 16) {
      pl[w * 16 + lane] = lA;
      pl[64 + w * 16 + lane] = lB;
    }
    if (c == 0) {
      #pragma unroll
      for (int j = 0; j < 4; ++j) {
        int tA = qb + w * 16 + lg4 + j;
        size_t pA = (size_t)(b * TSEQ + tA) * CDIM + hd * DH + lr;
        size_t pB = pA + (size_t)64 * CDIM;
        #pragma unroll
        for (int nd = 0; nd < 4; ++nd) {
          O[pA + nd * 16] = f2bu(oA[nd][j]);
          O[pB + nd * 16] = f2bu(oB[nd][j]);
        }
      }
    } else {
      uint16_t* Pb = Pbuf + (size_t)(bh * 31 + ebase_qt(qt) + (c - 1)) * 8192;
      #pragma unroll
      for (int j = 0; j < 4; ++j) {
        int qlA = w * 16 + lg4 + j;
        #pragma unroll
        for (int nd = 0; nd < 4; ++nd) {
          Pb[qlA * 64 + nd * 16 + lr] = f2bu(oA[nd][j]);
          Pb[(64 + qlA) * 64 + nd * 16 + lr] = f2bu(oB[nd][j]);
        }
      }
    }
  }
}

// ---------------- combine chunk partials in-place in Ob (vectorized ushort4) -------------
__global__ __launch_bounds__(256) void attn_reduce(
    const uint16_t* __restrict__ Pbuf, const float* __restrict__ Pl,
    uint16_t* __restrict__ O) {
  int rid = blockIdx.x;                // 0..503 = bh*21 + (qt-11)
  int bh = rid / 21, qt = 11 + (rid - bh * 21);
  int nch = (qt >= 22) ? 3 : 2;
  int b = bh / NH, hd = bh - b * NH;
  int tid = threadIdx.x;
  const float* pl = Pl + (size_t)(bh * 64 + lbase_qt(qt)) * 128;
  const uint16_t* pb = Pbuf + (size_t)(bh * 31 + ebase_qt(qt)) * 8192;
  #pragma unroll
  for (int it = 0; it < 8; ++it) {
    int idx = it * 256 + tid;          // 0..2047 = q*16 + dq
    int q = idx >> 4, dq = idx & 15;
    float lsum = pl[q] + pl[128 + q];
    if (nch == 3) lsum += pl[256 + q];
    float linv = 1.0f / lsum;
    int t = qt * 128 + q;
    size_t po = (size_t)(b * TSEQ + t) * CDIM + hd * DH + dq * 4;
    ushort4 ov = *(const ushort4*)&O[po];
    ushort4 pv = *(const ushort4*)&pb[q * 64 + dq * 4];
    float s0 = bu2f(ov.x) + bu2f(pv.x);
    float s1 = bu2f(ov.y) + bu2f(pv.y);
    float s2 = bu2f(ov.z) + bu2f(pv.z);
    float s3 = bu2f(ov.w) + bu2f(pv.w);
    if (nch == 3) {
      ushort4 pv2 = *(const ushort4*)&pb[8192 + q * 64 + dq * 4];
      s0 += bu2f(pv2.x); s1 += bu2f(pv2.y); s2 += bu2f(pv2.z); s3 += bu2f(pv2.w);
    }
    ushort4 o;
    o.x = f2bu(s0 * linv); o.y = f2bu(s1 * linv);
    o.z = f2bu(s2 * linv); o.w = f2bu(s3 * linv);
    *(ushort4*)&O[po] = o;
  }
}

extern "C" void kernel_launch(void* const* d_in, const int* in_sizes, int n_in,
                              void* d_out, int out_size, void* d_ws, size_t ws_size,
                              hipStream_t stream) {
  const float* x    = (const float*)d_in[0];
  const float* Wqkv = (const float*)d_in[1];
  const float* bqkv = (const float*)d_in[2];
  const float* Wout = (const float*)d_in[3];
  const float* bout = (const float*)d_in[4];
  float* out = (float*)d_out;
  char* ws = (char*)d_ws;

  uint16_t* Xb    = (uint16_t*)(ws + 0);          // 8192*768*2   = 12,582,912
  uint16_t* Wqkvt = (uint16_t*)(ws + 12582912);   // 2304*768*2   =  3,538,944
  uint16_t* Woutt = (uint16_t*)(ws + 16121856);   // 768*768*2    =  1,179,648
  uint16_t* Qb    = (uint16_t*)(ws + 17301504);   // 12,582,912 (pre-scaled)
  uint16_t* Kb    = (uint16_t*)(ws + 29884416);   // 12,582,912
  uint16_t* Vtb   = (uint16_t*)(ws + 42467328);   // 12,582,912 (V^T [B,H,Dh,T])
  uint16_t* Ob    = (uint16_t*)(ws + 55050240);   // 12,582,912 (end 67,633,152)
  // dead after gemm_qkv: reuse as split-KV partial buffers (no extra ws)
  uint16_t* Pbuf  = Xb;                           // [24*31][128][64] bf16 = 12,189,696
  float*    Pl    = (float*)Wqkvt;                // [24*64][128] f32 = 786,432

  cast_f32_bf16<<<2048, 256, 0, stream>>>(x, Xb, (MROWS * CDIM) / 4);
  transpose_cast<<<dim3(24, 72), 256, 0, stream>>>(Wqkv, Wqkvt, 768, 2304);
  transpose_cast<<<dim3(24, 24), 256, 0, stream>>>(Wout, Woutt, 768, 768);
  gemm_qkv<<<dim3(64, 18), 256, 0, stream>>>(Xb, Wqkvt, bqkv, Qb, Kb, Vtb, 2304, 768);
  attn_part<<<1512, 256, 0, stream>>>(Qb, Kb, Vtb, Ob, Pbuf, Pl);
  attn_reduce<<<504, 256, 0, stream>>>(Pbuf, Pl, Ob);
  gemm_out<<<dim3(64, 12), 256, 0, stream>>>(Ob, Woutt, bout, out, 768, 768);
}

// Round 20
// 165.089 us; speedup vs baseline: 1.0818x; 1.0288x over previous
//
#include <hip/hip_runtime.h>
#include <hip/hip_bf16.h>
#include <cstdint>

#define NH 12
#define DH 64
#define TSEQ 4096
#define BATCH 2
#define CDIM 768
#define MROWS (BATCH*TSEQ)

typedef __bf16 bf16x8 __attribute__((ext_vector_type(8)));
typedef __bf16 bf16x4 __attribute__((ext_vector_type(4)));
typedef bf16x8 bf16x8_a __attribute__((may_alias));
typedef bf16x4 bf16x4_a __attribute__((may_alias));
typedef float f32x4 __attribute__((ext_vector_type(4)));

__device__ __forceinline__ uint16_t f2bu(float f) {
  uint32_t u = __float_as_uint(f);
  u += 0x7fffu + ((u >> 16) & 1u);
  return (uint16_t)(u >> 16);
}

__device__ __forceinline__ float bu2f(uint16_t x) {
  return __uint_as_float(((uint32_t)x) << 16);
}

__device__ __forceinline__ void gload_lds16(const void* g, void* l) {
  __builtin_amdgcn_global_load_lds(
      (const __attribute__((address_space(1))) void*)g,
      (__attribute__((address_space(3))) void*)l, 16, 0, 0);
}

// ---------------- prep: fused cast(x) + transpose_cast(Wqkv) + transpose_cast(Wout) ------
// blocks 0..2047: cast x -> Xb (grid-stride float4)
// blocks 2048..3775: Wqkv [768][2304] -> Wqkvt [2304][768] bf16 (24x72 tiles)
// blocks 3776..4351: Wout [768][768] -> Woutt [768][768]^T bf16 (24x24 tiles)
__global__ __launch_bounds__(256) void prep(
    const float* __restrict__ x, uint16_t* __restrict__ xb,
    const float* __restrict__ wqkv, uint16_t* __restrict__ wqkvt,
    const float* __restrict__ wout, uint16_t* __restrict__ woutt) {
  __shared__ float tile[32][33];
  int bid = blockIdx.x;
  if (bid < 2048) {
    int n4 = (MROWS * CDIM) / 4;
    int i = bid * 256 + threadIdx.x;
    for (; i < n4; i += 2048 * 256) {
      float4 v = ((const float4*)x)[i];
      ushort4 o;
      o.x = f2bu(v.x); o.y = f2bu(v.y); o.z = f2bu(v.z); o.w = f2bu(v.w);
      ((ushort4*)xb)[i] = o;
    }
    return;
  }
  const float* w;
  uint16_t* wt;
  int K, N, kb, nb;
  if (bid < 3776) {
    int idx = bid - 2048;                 // 24 x 72
    w = wqkv; wt = wqkvt; K = 768; N = 2304;
    kb = (idx % 24) * 32; nb = (idx / 24) * 32;
  } else {
    int idx = bid - 3776;                 // 24 x 24
    w = wout; wt = woutt; K = 768; N = 768;
    kb = (idx % 24) * 32; nb = (idx / 24) * 32;
  }
  int tx = threadIdx.x & 31, ty = threadIdx.x >> 5;
  #pragma unroll
  for (int r = ty; r < 32; r += 8) tile[r][tx] = w[(size_t)(kb + r) * N + nb + tx];
  __syncthreads();
  #pragma unroll
  for (int r = ty; r < 32; r += 8) wt[(size_t)(nb + r) * K + kb + tx] = f2bu(tile[tx][r]);
}

// ---------------- QKV GEMM (BK=64, swizzled LDS): Q(pre-scaled)/K -> [B,H,T,Dh], V^T ----
__global__ __launch_bounds__(256) void gemm_qkv(
    const uint16_t* __restrict__ A, const uint16_t* __restrict__ Bt,
    const float* __restrict__ bias,
    uint16_t* __restrict__ q, uint16_t* __restrict__ k, uint16_t* __restrict__ v,
    int N, int K) {
  __shared__ __align__(16) uint16_t As[128 * 64];
  __shared__ __align__(16) uint16_t Bs[128 * 64];
  int tid = threadIdx.x;
  int w = tid >> 6, l = tid & 63;
  int lg = l >> 4, lr = l & 15;
  int mb = blockIdx.x * 128, nb = blockIdx.y * 128;
  int wr = (w >> 1) * 64, wc = (w & 1) * 64;
  f32x4 acc[4][4] = {};
  int srow = tid >> 3;                       // 0..31
  int schunk = (tid & 7) ^ (srow & 7);       // pre-swizzled source chunk
  const uint16_t* Ag = A + (size_t)(mb + srow) * K + schunk * 8;
  const uint16_t* Bg = Bt + (size_t)(nb + srow) * K + schunk * 8;
  char* AsB = (char*)As + (size_t)w * 1024;
  char* BsB = (char*)Bs + (size_t)w * 1024;
  size_t rowskip = (size_t)32 * K;
  for (int kb = 0; kb < K; kb += 64) {
    __syncthreads();
    #pragma unroll
    for (int r = 0; r < 4; ++r) {
      gload_lds16(Ag + kb + (size_t)r * rowskip, AsB + r * 4096);
      gload_lds16(Bg + kb + (size_t)r * rowskip, BsB + r * 4096);
    }
    __syncthreads();
    #pragma unroll
    for (int h = 0; h < 2; ++h) {
      bf16x8 af[4], bfr[4];
      #pragma unroll
      for (int i = 0; i < 4; ++i) {
        int rowA = wr + i * 16 + lr;
        af[i] = *(const bf16x8_a*)((const char*)As + rowA * 128 + (((lg + 4 * h) ^ (rowA & 7)) << 4));
        int rowB = wc + i * 16 + lr;
        bfr[i] = *(const bf16x8_a*)((const char*)Bs + rowB * 128 + (((lg + 4 * h) ^ (rowB & 7)) << 4));
      }
      #pragma unroll
      for (int mi = 0; mi < 4; ++mi)
        #pragma unroll
        for (int ni = 0; ni < 4; ++ni)
          acc[mi][ni] = __builtin_amdgcn_mfma_f32_16x16x32_bf16(af[mi], bfr[ni], acc[mi][ni], 0, 0, 0);
    }
  }
  #pragma unroll
  for (int mi = 0; mi < 4; ++mi) {
    #pragma unroll
    for (int ni = 0; ni < 4; ++ni) {
      int gm0 = mb + wr + mi * 16 + lg * 4;
      int gn = nb + wc + ni * 16 + lr;
      int which = gn / CDIM;
      int cc = gn - which * CDIM;
      int hh = cc >> 6, d = cc & 63;
      float bs = bias[gn];
      if (which == 2) {
        int b0 = gm0 >> 12, t0 = gm0 & 4095;
        ushort4 pk;
        pk.x = f2bu(acc[mi][ni][0] + bs);
        pk.y = f2bu(acc[mi][ni][1] + bs);
        pk.z = f2bu(acc[mi][ni][2] + bs);
        pk.w = f2bu(acc[mi][ni][3] + bs);
        *(ushort4*)&v[(((size_t)(b0 * NH + hh)) * DH + d) * TSEQ + t0] = pk;
      } else {
        uint16_t* dst = which ? k : q;
        float sc = which ? 1.0f : 0.1803368801111204f;  // 0.125 * log2(e)
        #pragma unroll
        for (int j = 0; j < 4; ++j) {
          int gm = gm0 + j;
          int bb = gm >> 12, t = gm & 4095;
          float val = (acc[mi][ni][j] + bs) * sc;
          dst[(((size_t)(bb * NH + hh)) * TSEQ + t) * DH + d] = f2bu(val);
        }
      }
    }
  }
}

// ---------------- out-proj GEMM (BK=64, swizzled LDS): BM=128, BN=64, grid 64x12 ----
__global__ __launch_bounds__(256) void gemm_out(
    const uint16_t* __restrict__ A, const uint16_t* __restrict__ Bt,
    const float* __restrict__ bias, float* __restrict__ outf, int N, int K) {
  __shared__ __align__(16) uint16_t As[128 * 64];
  __shared__ __align__(16) uint16_t Bs[64 * 64];
  int tid = threadIdx.x;
  int w = tid >> 6, l = tid & 63;
  int lg = l >> 4, lr = l & 15;
  int mb = blockIdx.x * 128, nb = blockIdx.y * 64;
  int wr = w * 32;
  f32x4 acc[2][4] = {};
  int srow = tid >> 3;
  int schunk = (tid & 7) ^ (srow & 7);
  const uint16_t* Ag = A + (size_t)(mb + srow) * K + schunk * 8;
  const uint16_t* Bg = Bt + (size_t)(nb + srow) * K + schunk * 8;
  char* AsB = (char*)As + (size_t)w * 1024;
  char* BsB = (char*)Bs + (size_t)w * 1024;
  size_t rowskip = (size_t)32 * K;
  for (int kb = 0; kb < K; kb += 64) {
    __syncthreads();
    #pragma unroll
    for (int r = 0; r < 4; ++r)
      gload_lds16(Ag + kb + (size_t)r * rowskip, AsB + r * 4096);
    #pragma unroll
    for (int r = 0; r < 2; ++r)
      gload_lds16(Bg + kb + (size_t)r * rowskip, BsB + r * 4096);
    __syncthreads();
    #pragma unroll
    for (int h = 0; h < 2; ++h) {
      bf16x8 af[2], bfr[4];
      #pragma unroll
      for (int i = 0; i < 2; ++i) {
        int rowA = wr + i * 16 + lr;
        af[i] = *(const bf16x8_a*)((const char*)As + rowA * 128 + (((lg + 4 * h) ^ (rowA & 7)) << 4));
      }
      #pragma unroll
      for (int i = 0; i < 4; ++i) {
        int rowB = i * 16 + lr;
        bfr[i] = *(const bf16x8_a*)((const char*)Bs + rowB * 128 + (((lg + 4 * h) ^ (rowB & 7)) << 4));
      }
      #pragma unroll
      for (int mi = 0; mi < 2; ++mi)
        #pragma unroll
        for (int ni = 0; ni < 4; ++ni)
          acc[mi][ni] = __builtin_amdgcn_mfma_f32_16x16x32_bf16(af[mi], bfr[ni], acc[mi][ni], 0, 0, 0);
    }
  }
  #pragma unroll
  for (int mi = 0; mi < 2; ++mi) {
    #pragma unroll
    for (int ni = 0; ni < 4; ++ni) {
      #pragma unroll
      for (int j = 0; j < 4; ++j) {
        int gm = mb + wr + mi * 16 + lg * 4 + j;
        int gn = nb + ni * 16 + lr;
        outf[(size_t)gm * N + gn] = acc[mi][ni][j] + bias[gn];
      }
    }
  }
}

// lsum slot base within [64] per qt (multi-chunk qt only: 11..31)
__device__ __forceinline__ int lbase_qt(int qt) {
  return (qt < 22) ? (qt - 11) * 2 : 22 + (qt - 22) * 3;
}
// Pbuf extra-chunk slot base within [31] per qt
__device__ __forceinline__ int ebase_qt(int qt) {
  return (qt < 22) ? (qt - 11) : 11 + (qt - 22) * 2;
}

// ---------------- flash attention (r16-exact best: 89.5 µs) ----------------
__global__ __launch_bounds__(256) void attn_part(
    const uint16_t* __restrict__ Q, const uint16_t* __restrict__ K,
    const uint16_t* __restrict__ Vt, uint16_t* __restrict__ O,
    uint16_t* __restrict__ Pbuf, float* __restrict__ Pl) {
  int gid = blockIdx.x;
  int widx = gid / 24, bh = gid - widx * 24;
  int qt, c, nch;
  if (widx < 30) { qt = 31 - widx / 3; c = widx % 3; nch = 3; }
  else if (widx < 52) { int u = widx - 30; qt = 21 - (u >> 1); c = u & 1; nch = 2; }
  else { qt = 62 - widx; c = 0; nch = 1; }
  int ntile = 2 * qt + 2;
  int L = (ntile + nch - 1) / nch;
  int t0 = c * L;
  int t1 = min(ntile - 1, t0 + L - 1);

  int b = bh / NH, hd = bh - b * NH;
  size_t base = (size_t)bh * TSEQ * DH;
  int tid = threadIdx.x, w = tid >> 6, lane = tid & 63;
  int lg = lane >> 4, lr = lane & 15;
  __shared__ __align__(16) uint16_t Ks[64 * 64];
  __shared__ __align__(16) uint16_t Vs[64 * 64];
  __shared__ uint16_t Ps[4][16 * 64];
  char* pw = (char*)Ps[w];
  int srow = tid >> 3;
  int schunk = (tid & 7) ^ (srow & 7);
  const uint16_t* Kg0 = K + base + (size_t)srow * DH + schunk * 8;
  const uint16_t* Vg0 = Vt + base + (size_t)srow * TSEQ + schunk * 8;
  char* KsB = (char*)Ks + w * 1024;
  char* VsB = (char*)Vs + w * 1024;
  int swzA = (lg ^ (lr & 7)) << 4;
  int swzB = swzA ^ 64;

  int qb = qt * 128;
  int qgA = qb + w * 16 + lr;
  int qgB = qgA + 64;
  bf16x8 qA0 = *(const bf16x8_a*)(const void*)(Q + base + (size_t)qgA * DH + lg * 8);
  bf16x8 qA1 = *(const bf16x8_a*)(const void*)(Q + base + (size_t)qgA * DH + 32 + lg * 8);
  bf16x8 qB0 = *(const bf16x8_a*)(const void*)(Q + base + (size_t)qgB * DH + lg * 8);
  bf16x8 qB1 = *(const bf16x8_a*)(const void*)(Q + base + (size_t)qgB * DH + 32 + lg * 8);
  f32x4 oA[4] = {}, oB[4] = {};
  float lA = 0.f, lB = 0.f;
  int lg4 = lg * 4;
  int pofs = (lg & 1) * 8;

  for (int t = t0; t <= t1; ++t) {
    __syncthreads();
    {
      const uint16_t* kg_ = Kg0 + (size_t)t * (64 * DH);
      const uint16_t* vg_ = Vg0 + (size_t)t * 64;
      gload_lds16(kg_,           KsB);
      gload_lds16(kg_ + 32 * DH, KsB + 4096);
      gload_lds16(vg_,                     VsB);
      gload_lds16(vg_ + (size_t)32 * TSEQ, VsB + 4096);
    }
    __syncthreads();
    bool doA = (t <= 2 * qt);
    int kb0 = t * 64;
    f32x4 sA[4], sB[4];
    __builtin_amdgcn_s_setprio(1);
    #pragma unroll
    for (int ni = 0; ni < 4; ++ni) {
      const char* kbp = (const char*)Ks + (ni * 16 + lr) * 128;
      bf16x8 kf0 = *(const bf16x8_a*)(kbp + swzA);
      bf16x8 kf1 = *(const bf16x8_a*)(kbp + swzB);
      f32x4 s = {};
      s = __builtin_amdgcn_mfma_f32_16x16x32_bf16(kf0, qB0, s, 0, 0, 0);
      s = __builtin_amdgcn_mfma_f32_16x16x32_bf16(kf1, qB1, s, 0, 0, 0);
      sB[ni] = s;
      if (doA) {
        f32x4 sa = {};
        sa = __builtin_amdgcn_mfma_f32_16x16x32_bf16(kf0, qA0, sa, 0, 0, 0);
        sa = __builtin_amdgcn_mfma_f32_16x16x32_bf16(kf1, qA1, sa, 0, 0, 0);
        sA[ni] = sa;
      }
    }
    __builtin_amdgcn_s_setprio(0);
    bf16x8 pfA0, pfA1;
    if (doA) {
      if (t == 2 * qt) {
        int thr = qgA - kb0 - lg4;
        #pragma unroll
        for (int ni = 0; ni < 4; ++ni)
          #pragma unroll
          for (int j = 0; j < 4; ++j)
            sA[ni][j] = (16 * ni + j <= thr) ? sA[ni][j] : -1e30f;
      }
      #pragma unroll
      for (int ni = 0; ni < 4; ++ni) {
        float p0 = __builtin_amdgcn_exp2f(sA[ni][0]);
        float p1 = __builtin_amdgcn_exp2f(sA[ni][1]);
        float p2 = __builtin_amdgcn_exp2f(sA[ni][2]);
        float p3 = __builtin_amdgcn_exp2f(sA[ni][3]);
        lA += (p0 + p1) + (p2 + p3);
        bf16x4 pk;
        pk[0] = (__bf16)p0; pk[1] = (__bf16)p1; pk[2] = (__bf16)p2; pk[3] = (__bf16)p3;
        int chunkc = (2 * ni + (lg >> 1)) ^ (lr & 7);
        *(bf16x4_a*)(pw + lr * 128 + chunkc * 16 + pofs) = pk;
      }
      pfA0 = *(const bf16x8_a*)(pw + lr * 128 + swzA);
      pfA1 = *(const bf16x8_a*)(pw + lr * 128 + swzB);
    }
    {
      if (t == 2 * qt + 1) {
        int thr = qgB - kb0 - lg4;
        #pragma unroll
        for (int ni = 0; ni < 4; ++ni)
          #pragma unroll
          for (int j = 0; j < 4; ++j)
            sB[ni][j] = (16 * ni + j <= thr) ? sB[ni][j] : -1e30f;
      }
      #pragma unroll
      for (int ni = 0; ni < 4; ++ni) {
        float p0 = __builtin_amdgcn_exp2f(sB[ni][0]);
        float p1 = __builtin_amdgcn_exp2f(sB[ni][1]);
        float p2 = __builtin_amdgcn_exp2f(sB[ni][2]);
        float p3 = __builtin_amdgcn_exp2f(sB[ni][3]);
        lB += (p0 + p1) + (p2 + p3);
        bf16x4 pk;
        pk[0] = (__bf16)p0; pk[1] = (__bf16)p1; pk[2] = (__bf16)p2; pk[3] = (__bf16)p3;
        int chunkc = (2 * ni + (lg >> 1)) ^ (lr & 7);
        *(bf16x4_a*)(pw + lr * 128 + chunkc * 16 + pofs) = pk;
      }
    }
    bf16x8 pfB0 = *(const bf16x8_a*)(pw + lr * 128 + swzA);
    bf16x8 pfB1 = *(const bf16x8_a*)(pw + lr * 128 + swzB);
    __builtin_amdgcn_s_setprio(1);
    #pragma unroll
    for (int nd = 0; nd < 4; ++nd) {
      const char* vb = (const char*)Vs + (nd * 16 + lr) * 128;
      bf16x8 vf0 = *(const bf16x8_a*)(vb + swzA);
      bf16x8 vf1 = *(const bf16x8_a*)(vb + swzB);
      oB[nd] = __builtin_amdgcn_mfma_f32_16x16x32_bf16(pfB0, vf0, oB[nd], 0, 0, 0);
      oB[nd] = __builtin_amdgcn_mfma_f32_16x16x32_bf16(pfB1, vf1, oB[nd], 0, 0, 0);
      if (doA) {
        oA[nd] = __builtin_amdgcn_mfma_f32_16x16x32_bf16(pfA0, vf0, oA[nd], 0, 0, 0);
        oA[nd] = __builtin_amdgcn_mfma_f32_16x16x32_bf16(pfA1, vf1, oA[nd], 0, 0, 0);
      }
    }
    __builtin_amdgcn_s_setprio(0);
  }

  lA += __shfl_xor(lA, 16, 64); lA += __shfl_xor(lA, 32, 64);
  lB += __shfl_xor(lB, 16, 64); lB += __shfl_xor(lB, 32, 64);
  if (nch == 1) {
    float riA = 1.0f / lA, riB = 1.0f / lB;
    #pragma unroll
    for (int j = 0; j < 4; ++j) {
      float rvA = __shfl(riA, (lane & 48) | (lg4 + j), 64);
      float rvB = __shfl(riB, (lane & 48) | (lg4 + j), 64);
      int tA = qb + w * 16 + lg4 + j;
      size_t pA = (size_t)(b * TSEQ + tA) * CDIM + hd * DH + lr;
      size_t pB = pA + (size_t)64 * CDIM;
      #pragma unroll
      for (int nd = 0; nd < 4; ++nd) {
        O[pA + nd * 16] = f2bu(oA[nd][j] * rvA);
        O[pB + nd * 16] = f2bu(oB[nd][j] * rvB);
      }
    }
  } else {
    float* pl = Pl + (size_t)(bh * 64 + lbase_qt(qt) + c) * 128;
    if (lane < 16) {
      pl[w * 16 + lane] = lA;
      pl[64 + w * 16 + lane] = lB;
    }
    if (c == 0) {
      #pragma unroll
      for (int j = 0; j < 4; ++j) {
        int tA = qb + w * 16 + lg4 + j;
        size_t pA = (size_t)(b * TSEQ + tA) * CDIM + hd * DH + lr;
        size_t pB = pA + (size_t)64 * CDIM;
        #pragma unroll
        for (int nd = 0; nd < 4; ++nd) {
          O[pA + nd * 16] = f2bu(oA[nd][j]);
          O[pB + nd * 16] = f2bu(oB[nd][j]);
        }
      }
    } else {
      uint16_t* Pb = Pbuf + (size_t)(bh * 31 + ebase_qt(qt) + (c - 1)) * 8192;
      #pragma unroll
      for (int j = 0; j < 4; ++j) {
        int qlA = w * 16 + lg4 + j;
        #pragma unroll
        for (int nd = 0; nd < 4; ++nd) {
          Pb[qlA * 64 + nd * 16 + lr] = f2bu(oA[nd][j]);
          Pb[(64 + qlA) * 64 + nd * 16 + lr] = f2bu(oB[nd][j]);
        }
      }
    }
  }
}

// ---------------- combine chunk partials in-place in Ob (vectorized ushort4) -------------
__global__ __launch_bounds__(256) void attn_reduce(
    const uint16_t* __restrict__ Pbuf, const float* __restrict__ Pl,
    uint16_t* __restrict__ O) {
  int rid = blockIdx.x;                // 0..503 = bh*21 + (qt-11)
  int bh = rid / 21, qt = 11 + (rid - bh * 21);
  int nch = (qt >= 22) ? 3 : 2;
  int b = bh / NH, hd = bh - b * NH;
  int tid = threadIdx.x;
  const float* pl = Pl + (size_t)(bh * 64 + lbase_qt(qt)) * 128;
  const uint16_t* pb = Pbuf + (size_t)(bh * 31 + ebase_qt(qt)) * 8192;
  #pragma unroll
  for (int it = 0; it < 8; ++it) {
    int idx = it * 256 + tid;          // 0..2047 = q*16 + dq
    int q = idx >> 4, dq = idx & 15;
    float lsum = pl[q] + pl[128 + q];
    if (nch == 3) lsum += pl[256 + q];
    float linv = 1.0f / lsum;
    int t = qt * 128 + q;
    size_t po = (size_t)(b * TSEQ + t) * CDIM + hd * DH + dq * 4;
    ushort4 ov = *(const ushort4*)&O[po];
    ushort4 pv = *(const ushort4*)&pb[q * 64 + dq * 4];
    float s0 = bu2f(ov.x) + bu2f(pv.x);
    float s1 = bu2f(ov.y) + bu2f(pv.y);
    float s2 = bu2f(ov.z) + bu2f(pv.z);
    float s3 = bu2f(ov.w) + bu2f(pv.w);
    if (nch == 3) {
      ushort4 pv2 = *(const ushort4*)&pb[8192 + q * 64 + dq * 4];
      s0 += bu2f(pv2.x); s1 += bu2f(pv2.y); s2 += bu2f(pv2.z); s3 += bu2f(pv2.w);
    }
    ushort4 o;
    o.x = f2bu(s0 * linv); o.y = f2bu(s1 * linv);
    o.z = f2bu(s2 * linv); o.w = f2bu(s3 * linv);
    *(ushort4*)&O[po] = o;
  }
}

extern "C" void kernel_launch(void* const* d_in, const int* in_sizes, int n_in,
                              void* d_out, int out_size, void* d_ws, size_t ws_size,
                              hipStream_t stream) {
  const float* x    = (const float*)d_in[0];
  const float* Wqkv = (const float*)d_in[1];
  const float* bqkv = (const float*)d_in[2];
  const float* Wout = (const float*)d_in[3];
  const float* bout = (const float*)d_in[4];
  float* out = (float*)d_out;
  char* ws = (char*)d_ws;

  uint16_t* Xb    = (uint16_t*)(ws + 0);          // 8192*768*2   = 12,582,912
  uint16_t* Wqkvt = (uint16_t*)(ws + 12582912);   // 2304*768*2   =  3,538,944
  uint16_t* Woutt = (uint16_t*)(ws + 16121856);   // 768*768*2    =  1,179,648
  uint16_t* Qb    = (uint16_t*)(ws + 17301504);   // 12,582,912 (pre-scaled)
  uint16_t* Kb    = (uint16_t*)(ws + 29884416);   // 12,582,912
  uint16_t* Vtb   = (uint16_t*)(ws + 42467328);   // 12,582,912 (V^T [B,H,Dh,T])
  uint16_t* Ob    = (uint16_t*)(ws + 55050240);   // 12,582,912 (end 67,633,152)
  // dead after gemm_qkv: reuse as split-KV partial buffers (no extra ws)
  uint16_t* Pbuf  = Xb;                           // [24*31][128][64] bf16 = 12,189,696
  float*    Pl    = (float*)Wqkvt;                // [24*64][128] f32 = 786,432

  prep<<<4352, 256, 0, stream>>>(x, Xb, Wqkv, Wqkvt, Wout, Woutt);
  gemm_qkv<<<dim3(64, 18), 256, 0, stream>>>(Xb, Wqkvt, bqkv, Qb, Kb, Vtb, 2304, 768);
  attn_part<<<1512, 256, 0, stream>>>(Qb, Kb, Vtb, Ob, Pbuf, Pl);
  attn_reduce<<<504, 256, 0, stream>>>(Pbuf, Pl, Ob);
  gemm_out<<<dim3(64, 12), 256, 0, stream>>>(Ob, Woutt, bout, out, 768, 768);
}

// Round 21
// 164.877 us; speedup vs baseline: 1.0832x; 1.0013x over previous
//
#include <hip/hip_runtime.h>
#include <hip/hip_bf16.h>
#include <cstdint>

#define NH 12
#define DH 64
#define TSEQ 4096
#define BATCH 2
#define CDIM 768
#define MROWS (BATCH*TSEQ)

typedef __bf16 bf16x8 __attribute__((ext_vector_type(8)));
typedef __bf16 bf16x4 __attribute__((ext_vector_type(4)));
typedef bf16x8 bf16x8_a __attribute__((may_alias));
typedef bf16x4 bf16x4_a __attribute__((may_alias));
typedef float f32x4 __attribute__((ext_vector_type(4)));
typedef uint32_t u32;

__device__ __forceinline__ uint16_t f2bu(float f) {
  uint32_t u = __float_as_uint(f);
  u += 0x7fffu + ((u >> 16) & 1u);
  return (uint16_t)(u >> 16);
}

__device__ __forceinline__ float bu2f(uint16_t x) {
  return __uint_as_float(((uint32_t)x) << 16);
}

__device__ __forceinline__ bf16x8 ones_frag() {
  union { u32 u[4]; bf16x8 v; } t;
  t.u[0] = 0x3F803F80u; t.u[1] = 0x3F803F80u;
  t.u[2] = 0x3F803F80u; t.u[3] = 0x3F803F80u;
  return t.v;
}

__device__ __forceinline__ void gload_lds16(const void* g, void* l) {
  __builtin_amdgcn_global_load_lds(
      (const __attribute__((address_space(1))) void*)g,
      (__attribute__((address_space(3))) void*)l, 16, 0, 0);
}

// ---------------- prep: fused cast(x) + transpose_cast(Wqkv) + transpose_cast(Wout) ------
__global__ __launch_bounds__(256) void prep(
    const float* __restrict__ x, uint16_t* __restrict__ xb,
    const float* __restrict__ wqkv, uint16_t* __restrict__ wqkvt,
    const float* __restrict__ wout, uint16_t* __restrict__ woutt) {
  __shared__ float tile[32][33];
  int bid = blockIdx.x;
  if (bid < 2048) {
    int n4 = (MROWS * CDIM) / 4;
    int i = bid * 256 + threadIdx.x;
    for (; i < n4; i += 2048 * 256) {
      float4 v = ((const float4*)x)[i];
      ushort4 o;
      o.x = f2bu(v.x); o.y = f2bu(v.y); o.z = f2bu(v.z); o.w = f2bu(v.w);
      ((ushort4*)xb)[i] = o;
    }
    return;
  }
  const float* w;
  uint16_t* wt;
  int K, N, kb, nb;
  if (bid < 3776) {
    int idx = bid - 2048;                 // 24 x 72
    w = wqkv; wt = wqkvt; K = 768; N = 2304;
    kb = (idx % 24) * 32; nb = (idx / 24) * 32;
  } else {
    int idx = bid - 3776;                 // 24 x 24
    w = wout; wt = woutt; K = 768; N = 768;
    kb = (idx % 24) * 32; nb = (idx / 24) * 32;
  }
  int tx = threadIdx.x & 31, ty = threadIdx.x >> 5;
  #pragma unroll
  for (int r = ty; r < 32; r += 8) tile[r][tx] = w[(size_t)(kb + r) * N + nb + tx];
  __syncthreads();
  #pragma unroll
  for (int r = ty; r < 32; r += 8) wt[(size_t)(nb + r) * K + kb + tx] = f2bu(tile[tx][r]);
}

// ---------------- QKV GEMM (BK=64, swizzled LDS): Q(pre-scaled)/K -> [B,H,T,Dh], V^T ----
__global__ __launch_bounds__(256) void gemm_qkv(
    const uint16_t* __restrict__ A, const uint16_t* __restrict__ Bt,
    const float* __restrict__ bias,
    uint16_t* __restrict__ q, uint16_t* __restrict__ k, uint16_t* __restrict__ v,
    int N, int K) {
  __shared__ __align__(16) uint16_t As[128 * 64];
  __shared__ __align__(16) uint16_t Bs[128 * 64];
  int tid = threadIdx.x;
  int w = tid >> 6, l = tid & 63;
  int lg = l >> 4, lr = l & 15;
  int mb = blockIdx.x * 128, nb = blockIdx.y * 128;
  int wr = (w >> 1) * 64, wc = (w & 1) * 64;
  f32x4 acc[4][4] = {};
  int srow = tid >> 3;                       // 0..31
  int schunk = (tid & 7) ^ (srow & 7);       // pre-swizzled source chunk
  const uint16_t* Ag = A + (size_t)(mb + srow) * K + schunk * 8;
  const uint16_t* Bg = Bt + (size_t)(nb + srow) * K + schunk * 8;
  char* AsB = (char*)As + (size_t)w * 1024;
  char* BsB = (char*)Bs + (size_t)w * 1024;
  size_t rowskip = (size_t)32 * K;
  for (int kb = 0; kb < K; kb += 64) {
    __syncthreads();
    #pragma unroll
    for (int r = 0; r < 4; ++r) {
      gload_lds16(Ag + kb + (size_t)r * rowskip, AsB + r * 4096);
      gload_lds16(Bg + kb + (size_t)r * rowskip, BsB + r * 4096);
    }
    __syncthreads();
    #pragma unroll
    for (int h = 0; h < 2; ++h) {
      bf16x8 af[4], bfr[4];
      #pragma unroll
      for (int i = 0; i < 4; ++i) {
        int rowA = wr + i * 16 + lr;
        af[i] = *(const bf16x8_a*)((const char*)As + rowA * 128 + (((lg + 4 * h) ^ (rowA & 7)) << 4));
        int rowB = wc + i * 16 + lr;
        bfr[i] = *(const bf16x8_a*)((const char*)Bs + rowB * 128 + (((lg + 4 * h) ^ (rowB & 7)) << 4));
      }
      #pragma unroll
      for (int mi = 0; mi < 4; ++mi)
        #pragma unroll
        for (int ni = 0; ni < 4; ++ni)
          acc[mi][ni] = __builtin_amdgcn_mfma_f32_16x16x32_bf16(af[mi], bfr[ni], acc[mi][ni], 0, 0, 0);
    }
  }
  #pragma unroll
  for (int mi = 0; mi < 4; ++mi) {
    #pragma unroll
    for (int ni = 0; ni < 4; ++ni) {
      int gm0 = mb + wr + mi * 16 + lg * 4;
      int gn = nb + wc + ni * 16 + lr;
      int which = gn / CDIM;
      int cc = gn - which * CDIM;
      int hh = cc >> 6, d = cc & 63;
      float bs = bias[gn];
      if (which == 2) {
        int b0 = gm0 >> 12, t0 = gm0 & 4095;
        ushort4 pk;
        pk.x = f2bu(acc[mi][ni][0] + bs);
        pk.y = f2bu(acc[mi][ni][1] + bs);
        pk.z = f2bu(acc[mi][ni][2] + bs);
        pk.w = f2bu(acc[mi][ni][3] + bs);
        *(ushort4*)&v[(((size_t)(b0 * NH + hh)) * DH + d) * TSEQ + t0] = pk;
      } else {
        uint16_t* dst = which ? k : q;
        float sc = which ? 1.0f : 0.1803368801111204f;  // 0.125 * log2(e)
        #pragma unroll
        for (int j = 0; j < 4; ++j) {
          int gm = gm0 + j;
          int bb = gm >> 12, t = gm & 4095;
          float val = (acc[mi][ni][j] + bs) * sc;
          dst[(((size_t)(bb * NH + hh)) * TSEQ + t) * DH + d] = f2bu(val);
        }
      }
    }
  }
}

// ---------------- out-proj GEMM (BK=64, swizzled LDS): BM=128, BN=64, grid 64x12 ----
__global__ __launch_bounds__(256) void gemm_out(
    const uint16_t* __restrict__ A, const uint16_t* __restrict__ Bt,
    const float* __restrict__ bias, float* __restrict__ outf, int N, int K) {
  __shared__ __align__(16) uint16_t As[128 * 64];
  __shared__ __align__(16) uint16_t Bs[64 * 64];
  int tid = threadIdx.x;
  int w = tid >> 6, l = tid & 63;
  int lg = l >> 4, lr = l & 15;
  int mb = blockIdx.x * 128, nb = blockIdx.y * 64;
  int wr = w * 32;
  f32x4 acc[2][4] = {};
  int srow = tid >> 3;
  int schunk = (tid & 7) ^ (srow & 7);
  const uint16_t* Ag = A + (size_t)(mb + srow) * K + schunk * 8;
  const uint16_t* Bg = Bt + (size_t)(nb + srow) * K + schunk * 8;
  char* AsB = (char*)As + (size_t)w * 1024;
  char* BsB = (char*)Bs + (size_t)w * 1024;
  size_t rowskip = (size_t)32 * K;
  for (int kb = 0; kb < K; kb += 64) {
    __syncthreads();
    #pragma unroll
    for (int r = 0; r < 4; ++r)
      gload_lds16(Ag + kb + (size_t)r * rowskip, AsB + r * 4096);
    #pragma unroll
    for (int r = 0; r < 2; ++r)
      gload_lds16(Bg + kb + (size_t)r * rowskip, BsB + r * 4096);
    __syncthreads();
    #pragma unroll
    for (int h = 0; h < 2; ++h) {
      bf16x8 af[2], bfr[4];
      #pragma unroll
      for (int i = 0; i < 2; ++i) {
        int rowA = wr + i * 16 + lr;
        af[i] = *(const bf16x8_a*)((const char*)As + rowA * 128 + (((lg + 4 * h) ^ (rowA & 7)) << 4));
      }
      #pragma unroll
      for (int i = 0; i < 4; ++i) {
        int rowB = i * 16 + lr;
        bfr[i] = *(const bf16x8_a*)((const char*)Bs + rowB * 128 + (((lg + 4 * h) ^ (rowB & 7)) << 4));
      }
      #pragma unroll
      for (int mi = 0; mi < 2; ++mi)
        #pragma unroll
        for (int ni = 0; ni < 4; ++ni)
          acc[mi][ni] = __builtin_amdgcn_mfma_f32_16x16x32_bf16(af[mi], bfr[ni], acc[mi][ni], 0, 0, 0);
    }
  }
  #pragma unroll
  for (int mi = 0; mi < 2; ++mi) {
    #pragma unroll
    for (int ni = 0; ni < 4; ++ni) {
      #pragma unroll
      for (int j = 0; j < 4; ++j) {
        int gm = mb + wr + mi * 16 + lg * 4 + j;
        int gn = nb + ni * 16 + lr;
        outf[(size_t)gm * N + gn] = acc[mi][ni][j] + bias[gn];
      }
    }
  }
}

// lsum slot base within [64] per qt (multi-chunk qt only: 11..31)
__device__ __forceinline__ int lbase_qt(int qt) {
  return (qt < 22) ? (qt - 11) * 2 : 22 + (qt - 22) * 3;
}
// Pbuf extra-chunk slot base within [31] per qt
__device__ __forceinline__ int ebase_qt(int qt) {
  return (qt < 22) ? (qt - 11) : 11 + (qt - 22) * 2;
}

// ---------------- flash attention: r16 structure + lsum via ones-MFMA ----------------
// Row-sum of P computed by 2 extra MFMAs per substep against an all-ones B-fragment:
// sum[j] = rowsum(q = w*16 + lg*4 + j), identical across lr lanes — exactly the layout
// the epilogue needs (no shuffle reductions, no broadcasts). Removes 32 VALU adds/tile.
__global__ __launch_bounds__(256) void attn_part(
    const uint16_t* __restrict__ Q, const uint16_t* __restrict__ K,
    const uint16_t* __restrict__ Vt, uint16_t* __restrict__ O,
    uint16_t* __restrict__ Pbuf, float* __restrict__ Pl) {
  int gid = blockIdx.x;
  int widx = gid / 24, bh = gid - widx * 24;
  int qt, c, nch;
  if (widx < 30) { qt = 31 - widx / 3; c = widx % 3; nch = 3; }
  else if (widx < 52) { int u = widx - 30; qt = 21 - (u >> 1); c = u & 1; nch = 2; }
  else { qt = 62 - widx; c = 0; nch = 1; }
  int ntile = 2 * qt + 2;
  int L = (ntile + nch - 1) / nch;
  int t0 = c * L;
  int t1 = min(ntile - 1, t0 + L - 1);

  int b = bh / NH, hd = bh - b * NH;
  size_t base = (size_t)bh * TSEQ * DH;
  int tid = threadIdx.x, w = tid >> 6, lane = tid & 63;
  int lg = lane >> 4, lr = lane & 15;
  __shared__ __align__(16) uint16_t Ks[64 * 64];
  __shared__ __align__(16) uint16_t Vs[64 * 64];
  __shared__ uint16_t Ps[4][16 * 64];
  char* pw = (char*)Ps[w];
  int srow = tid >> 3;
  int schunk = (tid & 7) ^ (srow & 7);
  const uint16_t* Kg0 = K + base + (size_t)srow * DH + schunk * 8;
  const uint16_t* Vg0 = Vt + base + (size_t)srow * TSEQ + schunk * 8;
  char* KsB = (char*)Ks + w * 1024;
  char* VsB = (char*)Vs + w * 1024;
  int swzA = (lg ^ (lr & 7)) << 4;
  int swzB = swzA ^ 64;

  int qb = qt * 128;
  int qgA = qb + w * 16 + lr;
  int qgB = qgA + 64;
  bf16x8 qA0 = *(const bf16x8_a*)(const void*)(Q + base + (size_t)qgA * DH + lg * 8);
  bf16x8 qA1 = *(const bf16x8_a*)(const void*)(Q + base + (size_t)qgA * DH + 32 + lg * 8);
  bf16x8 qB0 = *(const bf16x8_a*)(const void*)(Q + base + (size_t)qgB * DH + lg * 8);
  bf16x8 qB1 = *(const bf16x8_a*)(const void*)(Q + base + (size_t)qgB * DH + 32 + lg * 8);
  f32x4 oA[4] = {}, oB[4] = {};
  f32x4 sumA = {}, sumB = {};           // rowsum accumulators (ones-MFMA)
  int lg4 = lg * 4;
  int pofs = (lg & 1) * 8;
  bf16x8 onesf = ones_frag();

  for (int t = t0; t <= t1; ++t) {
    __syncthreads();
    {
      const uint16_t* kg_ = Kg0 + (size_t)t * (64 * DH);
      const uint16_t* vg_ = Vg0 + (size_t)t * 64;
      gload_lds16(kg_,           KsB);
      gload_lds16(kg_ + 32 * DH, KsB + 4096);
      gload_lds16(vg_,                     VsB);
      gload_lds16(vg_ + (size_t)32 * TSEQ, VsB + 4096);
    }
    __syncthreads();
    bool doA = (t <= 2 * qt);
    int kb0 = t * 64;
    f32x4 sA[4], sB[4];
    __builtin_amdgcn_s_setprio(1);
    #pragma unroll
    for (int ni = 0; ni < 4; ++ni) {
      const char* kbp = (const char*)Ks + (ni * 16 + lr) * 128;
      bf16x8 kf0 = *(const bf16x8_a*)(kbp + swzA);
      bf16x8 kf1 = *(const bf16x8_a*)(kbp + swzB);
      f32x4 s = {};
      s = __builtin_amdgcn_mfma_f32_16x16x32_bf16(kf0, qB0, s, 0, 0, 0);
      s = __builtin_amdgcn_mfma_f32_16x16x32_bf16(kf1, qB1, s, 0, 0, 0);
      sB[ni] = s;
      if (doA) {
        f32x4 sa = {};
        sa = __builtin_amdgcn_mfma_f32_16x16x32_bf16(kf0, qA0, sa, 0, 0, 0);
        sa = __builtin_amdgcn_mfma_f32_16x16x32_bf16(kf1, qA1, sa, 0, 0, 0);
        sA[ni] = sa;
      }
    }
    __builtin_amdgcn_s_setprio(0);
    bf16x8 pfA0, pfA1;
    if (doA) {
      if (t == 2 * qt) {
        int thr = qgA - kb0 - lg4;
        #pragma unroll
        for (int ni = 0; ni < 4; ++ni)
          #pragma unroll
          for (int j = 0; j < 4; ++j)
            sA[ni][j] = (16 * ni + j <= thr) ? sA[ni][j] : -1e30f;
      }
      #pragma unroll
      for (int ni = 0; ni < 4; ++ni) {
        float p0 = __builtin_amdgcn_exp2f(sA[ni][0]);
        float p1 = __builtin_amdgcn_exp2f(sA[ni][1]);
        float p2 = __builtin_amdgcn_exp2f(sA[ni][2]);
        float p3 = __builtin_amdgcn_exp2f(sA[ni][3]);
        bf16x4 pk;
        pk[0] = (__bf16)p0; pk[1] = (__bf16)p1; pk[2] = (__bf16)p2; pk[3] = (__bf16)p3;
        int chunkc = (2 * ni + (lg >> 1)) ^ (lr & 7);
        *(bf16x4_a*)(pw + lr * 128 + chunkc * 16 + pofs) = pk;
      }
      pfA0 = *(const bf16x8_a*)(pw + lr * 128 + swzA);
      pfA1 = *(const bf16x8_a*)(pw + lr * 128 + swzB);
    }
    {
      if (t == 2 * qt + 1) {
        int thr = qgB - kb0 - lg4;
        #pragma unroll
        for (int ni = 0; ni < 4; ++ni)
          #pragma unroll
          for (int j = 0; j < 4; ++j)
            sB[ni][j] = (16 * ni + j <= thr) ? sB[ni][j] : -1e30f;
      }
      #pragma unroll
      for (int ni = 0; ni < 4; ++ni) {
        float p0 = __builtin_amdgcn_exp2f(sB[ni][0]);
        float p1 = __builtin_amdgcn_exp2f(sB[ni][1]);
        float p2 = __builtin_amdgcn_exp2f(sB[ni][2]);
        float p3 = __builtin_amdgcn_exp2f(sB[ni][3]);
        bf16x4 pk;
        pk[0] = (__bf16)p0; pk[1] = (__bf16)p1; pk[2] = (__bf16)p2; pk[3] = (__bf16)p3;
        int chunkc = (2 * ni + (lg >> 1)) ^ (lr & 7);
        *(bf16x4_a*)(pw + lr * 128 + chunkc * 16 + pofs) = pk;
      }
    }
    bf16x8 pfB0 = *(const bf16x8_a*)(pw + lr * 128 + swzA);
    bf16x8 pfB1 = *(const bf16x8_a*)(pw + lr * 128 + swzB);
    __builtin_amdgcn_s_setprio(1);
    // lsum via ones-MFMA (D[q][*] = rowsum, identical across lr)
    sumB = __builtin_amdgcn_mfma_f32_16x16x32_bf16(pfB0, onesf, sumB, 0, 0, 0);
    sumB = __builtin_amdgcn_mfma_f32_16x16x32_bf16(pfB1, onesf, sumB, 0, 0, 0);
    if (doA) {
      sumA = __builtin_amdgcn_mfma_f32_16x16x32_bf16(pfA0, onesf, sumA, 0, 0, 0);
      sumA = __builtin_amdgcn_mfma_f32_16x16x32_bf16(pfA1, onesf, sumA, 0, 0, 0);
    }
    #pragma unroll
    for (int nd = 0; nd < 4; ++nd) {
      const char* vb = (const char*)Vs + (nd * 16 + lr) * 128;
      bf16x8 vf0 = *(const bf16x8_a*)(vb + swzA);
      bf16x8 vf1 = *(const bf16x8_a*)(vb + swzB);
      oB[nd] = __builtin_amdgcn_mfma_f32_16x16x32_bf16(pfB0, vf0, oB[nd], 0, 0, 0);
      oB[nd] = __builtin_amdgcn_mfma_f32_16x16x32_bf16(pfB1, vf1, oB[nd], 0, 0, 0);
      if (doA) {
        oA[nd] = __builtin_amdgcn_mfma_f32_16x16x32_bf16(pfA0, vf0, oA[nd], 0, 0, 0);
        oA[nd] = __builtin_amdgcn_mfma_f32_16x16x32_bf16(pfA1, vf1, oA[nd], 0, 0, 0);
      }
    }
    __builtin_amdgcn_s_setprio(0);
  }

  if (nch == 1) {
    #pragma unroll
    for (int j = 0; j < 4; ++j) {
      float rvA = 1.0f / sumA[j];       // rowsum for q-row lg4+j (uniform across lr)
      float rvB = 1.0f / sumB[j];
      int tA = qb + w * 16 + lg4 + j;
      size_t pA = (size_t)(b * TSEQ + tA) * CDIM + hd * DH + lr;
      size_t pB = pA + (size_t)64 * CDIM;
      #pragma unroll
      for (int nd = 0; nd < 4; ++nd) {
        O[pA + nd * 16] = f2bu(oA[nd][j] * rvA);
        O[pB + nd * 16] = f2bu(oB[nd][j] * rvB);
      }
    }
  } else {
    float* pl = Pl + (size_t)(bh * 64 + lbase_qt(qt) + c) * 128;
    if (lr == 0) {                      // 4 lanes (lg 0..3) cover rows 0..15 via float4
      *(float4*)&pl[w * 16 + lg4] = *(float4*)&sumA;
      *(float4*)&pl[64 + w * 16 + lg4] = *(float4*)&sumB;
    }
    if (c == 0) {
      #pragma unroll
      for (int j = 0; j < 4; ++j) {
        int tA = qb + w * 16 + lg4 + j;
        size_t pA = (size_t)(b * TSEQ + tA) * CDIM + hd * DH + lr;
        size_t pB = pA + (size_t)64 * CDIM;
        #pragma unroll
        for (int nd = 0; nd < 4; ++nd) {
          O[pA + nd * 16] = f2bu(oA[nd][j]);
          O[pB + nd * 16] = f2bu(oB[nd][j]);
        }
      }
    } else {
      uint16_t* Pb = Pbuf + (size_t)(bh * 31 + ebase_qt(qt) + (c - 1)) * 8192;
      #pragma unroll
      for (int j = 0; j < 4; ++j) {
        int qlA = w * 16 + lg4 + j;
        #pragma unroll
        for (int nd = 0; nd < 4; ++nd) {
          Pb[qlA * 64 + nd * 16 + lr] = f2bu(oA[nd][j]);
          Pb[(64 + qlA) * 64 + nd * 16 + lr] = f2bu(oB[nd][j]);
        }
      }
    }
  }
}

// ---------------- combine chunk partials in-place in Ob (vectorized ushort4) -------------
__global__ __launch_bounds__(256) void attn_reduce(
    const uint16_t* __restrict__ Pbuf, const float* __restrict__ Pl,
    uint16_t* __restrict__ O) {
  int rid = blockIdx.x;                // 0..503 = bh*21 + (qt-11)
  int bh = rid / 21, qt = 11 + (rid - bh * 21);
  int nch = (qt >= 22) ? 3 : 2;
  int b = bh / NH, hd = bh - b * NH;
  int tid = threadIdx.x;
  const float* pl = Pl + (size_t)(bh * 64 + lbase_qt(qt)) * 128;
  const uint16_t* pb = Pbuf + (size_t)(bh * 31 + ebase_qt(qt)) * 8192;
  #pragma unroll
  for (int it = 0; it < 8; ++it) {
    int idx = it * 256 + tid;          // 0..2047 = q*16 + dq
    int q = idx >> 4, dq = idx & 15;
    float lsum = pl[q] + pl[128 + q];
    if (nch == 3) lsum += pl[256 + q];
    float linv = 1.0f / lsum;
    int t = qt * 128 + q;
    size_t po = (size_t)(b * TSEQ + t) * CDIM + hd * DH + dq * 4;
    ushort4 ov = *(const ushort4*)&O[po];
    ushort4 pv = *(const ushort4*)&pb[q * 64 + dq * 4];
    float s0 = bu2f(ov.x) + bu2f(pv.x);
    float s1 = bu2f(ov.y) + bu2f(pv.y);
    float s2 = bu2f(ov.z) + bu2f(pv.z);
    float s3 = bu2f(ov.w) + bu2f(pv.w);
    if (nch == 3) {
      ushort4 pv2 = *(const ushort4*)&pb[8192 + q * 64 + dq * 4];
      s0 += bu2f(pv2.x); s1 += bu2f(pv2.y); s2 += bu2f(pv2.z); s3 += bu2f(pv2.w);
    }
    ushort4 o;
    o.x = f2bu(s0 * linv); o.y = f2bu(s1 * linv);
    o.z = f2bu(s2 * linv); o.w = f2bu(s3 * linv);
    *(ushort4*)&O[po] = o;
  }
}

extern "C" void kernel_launch(void* const* d_in, const int* in_sizes, int n_in,
                              void* d_out, int out_size, void* d_ws, size_t ws_size,
                              hipStream_t stream) {
  const float* x    = (const float*)d_in[0];
  const float* Wqkv = (const float*)d_in[1];
  const float* bqkv = (const float*)d_in[2];
  const float* Wout = (const float*)d_in[3];
  const float* bout = (const float*)d_in[4];
  float* out = (float*)d_out;
  char* ws = (char*)d_ws;

  uint16_t* Xb    = (uint16_t*)(ws + 0);          // 8192*768*2   = 12,582,912
  uint16_t* Wqkvt = (uint16_t*)(ws + 12582912);   // 2304*768*2   =  3,538,944
  uint16_t* Woutt = (uint16_t*)(ws + 16121856);   // 768*768*2    =  1,179,648
  uint16_t* Qb    = (uint16_t*)(ws + 17301504);   // 12,582,912 (pre-scaled)
  uint16_t* Kb    = (uint16_t*)(ws + 29884416);   // 12,582,912
  uint16_t* Vtb   = (uint16_t*)(ws + 42467328);   // 12,582,912 (V^T [B,H,Dh,T])
  uint16_t* Ob    = (uint16_t*)(ws + 55050240);   // 12,582,912 (end 67,633,152)
  // dead after gemm_qkv: reuse as split-KV partial buffers (no extra ws)
  uint16_t* Pbuf  = Xb;                           // [24*31][128][64] bf16 = 12,189,696
  float*    Pl    = (float*)Wqkvt;                // [24*64][128] f32 = 786,432

  prep<<<4352, 256, 0, stream>>>(x, Xb, Wqkv, Wqkvt, Wout, Woutt);
  gemm_qkv<<<dim3(64, 18), 256, 0, stream>>>(Xb, Wqkvt, bqkv, Qb, Kb, Vtb, 2304, 768);
  attn_part<<<1512, 256, 0, stream>>>(Qb, Kb, Vtb, Ob, Pbuf, Pl);
  attn_reduce<<<504, 256, 0, stream>>>(Pbuf, Pl, Ob);
  gemm_out<<<dim3(64, 12), 256, 0, stream>>>(Ob, Woutt, bout, out, 768, 768);
}